// Round 1
// baseline (2531.762 us; speedup 1.0000x reference)
//
#include <hip/hip_runtime.h>
#include <hip/hip_bf16.h>

#define NB_ 32
#define NN_ 128
#define HH_ 128
#define LL_ 3
#define EE_ 65536
#define NODES_ 4096
#define SLOTS_ 524288   // NODES_ * NN_
#define NEGV -1e9f

// ---------------- node encoder: node_fts[v][t] = sum_c atom_emb[c, x[v,c], t]
__global__ __launch_bounds__(128) void k_node_enc(const int* __restrict__ x,
    const float* __restrict__ atom_emb, float* __restrict__ node_fts) {
  int v = blockIdx.x, t = threadIdx.x;
  float acc = 0.f;
#pragma unroll
  for (int c = 0; c < 9; c++) {
    int xv = x[v * 9 + c];
    acc += atom_emb[(c * 128 + xv) * 128 + t];
  }
  node_fts[v * 128 + t] = acc;
}

// ---------------- edge histogram into receiver-major pair slots
__global__ __launch_bounds__(256) void k_edge_count(const int* __restrict__ ei,
                                                    int* __restrict__ cnt) {
  int e = blockIdx.x * 256 + threadIdx.x;
  int s = ei[e], d = ei[EE_ + e];
  int g = s >> 7, i = s & 127, j = d & 127;
  int slot = ((g << 7) + j) * 128 + i;   // receiver-major
  atomicAdd(&cnt[slot], 1);
}

// ---------------- 3-kernel exclusive scan over 524288 ints
__global__ __launch_bounds__(256) void k_scan1(const int* __restrict__ cnt,
    int* __restrict__ base, int* __restrict__ bsum) {
  __shared__ int s[256];
  int t = threadIdx.x, gid = blockIdx.x * 256 + t;
  int v = cnt[gid];
  s[t] = v; __syncthreads();
  for (int st = 1; st < 256; st <<= 1) {
    int a = s[t]; int b = (t >= st) ? s[t - st] : 0;
    __syncthreads(); s[t] = a + b; __syncthreads();
  }
  base[gid] = s[t] - v;
  if (t == 255) bsum[blockIdx.x] = s[255];
}

__global__ __launch_bounds__(256) void k_scan2(int* __restrict__ bsum) {
  __shared__ int s[256];
  int t = threadIdx.x;
  int v[8]; int tot = 0;
#pragma unroll
  for (int q = 0; q < 8; q++) { v[q] = bsum[t * 8 + q]; tot += v[q]; }
  s[t] = tot; __syncthreads();
  for (int st = 1; st < 256; st <<= 1) {
    int a = s[t]; int b = (t >= st) ? s[t - st] : 0;
    __syncthreads(); s[t] = a + b; __syncthreads();
  }
  int run = s[t] - tot;
#pragma unroll
  for (int q = 0; q < 8; q++) { int tmp = v[q]; bsum[t * 8 + q] = run; run += tmp; }
}

__global__ __launch_bounds__(256) void k_scan3(int* __restrict__ base,
    int* __restrict__ cursor, const int* __restrict__ bsum) {
  int gid = blockIdx.x * 256 + threadIdx.x;
  int v = base[gid] + bsum[gid >> 8];
  base[gid] = v; cursor[gid] = v;
  if (gid == 0) base[SLOTS_] = EE_;
}

// ---------------- scatter edge ids into sorted order
__global__ __launch_bounds__(256) void k_edge_scatter(const int* __restrict__ ei,
    int* __restrict__ cursor, int* __restrict__ sorted_e) {
  int e = blockIdx.x * 256 + threadIdx.x;
  int s = ei[e], d = ei[EE_ + e];
  int g = s >> 7, i = s & 127, j = d & 127;
  int slot = ((g << 7) + j) * 128 + i;
  int pos = atomicAdd(&cursor[slot], 1);
  sorted_e[pos] = e;
}

// ---------------- m1/m2: [4096,256] @ [256,128] x2, 8 nodes per block
__global__ __launch_bounds__(256) void k_m12(const float* __restrict__ nf,
    const float* __restrict__ hid,
    const float* __restrict__ Wm1, const float* __restrict__ bm1,
    const float* __restrict__ Wm2, const float* __restrict__ bm2,
    float* __restrict__ m1, float* __restrict__ m2, int l) {
  __shared__ float zb[8][256];
  int v0 = blockIdx.x * 8, tid = threadIdx.x;
#pragma unroll
  for (int n = 0; n < 8; n++)
    zb[n][tid] = (tid < 128) ? nf[(v0 + n) * 128 + tid]
                             : hid[(v0 + n) * 128 + (tid - 128)];
  __syncthreads();
  int hs = tid >> 7, c = tid & 127;
  const float* W = (hs ? Wm2 : Wm1) + l * 32768;
  float bv = (hs ? bm2 : bm1)[l * 128 + c];
  float acc[8];
#pragma unroll
  for (int n = 0; n < 8; n++) acc[n] = bv;
  for (int k = 0; k < 256; k++) {
    float w = W[k * 128 + c];
#pragma unroll
    for (int n = 0; n < 8; n++) acc[n] += zb[n][k] * w;
  }
  float* out = hs ? m2 : m1;
#pragma unroll
  for (int n = 0; n < 8; n++) out[(v0 + n) * 128 + c] = acc[n];
}

// ---------------- core: per-receiver sparse pair MLP + masked max
__global__ __launch_bounds__(256) void k_pairmlp(
    const float* __restrict__ m1, const float* __restrict__ m2,
    const int* __restrict__ base, const int* __restrict__ sorted_e,
    const int* __restrict__ edge_attr, const float* __restrict__ bond_emb,
    const float* __restrict__ We, const float* __restrict__ be,
    const float* __restrict__ bg,
    const float* __restrict__ Wp1, const float* __restrict__ bp1,
    const float* __restrict__ Wp2, const float* __restrict__ bp2,
    float* __restrict__ msgs, int l) {
  __shared__ float Wlds[128 * 128];   // 64 KB current weight [k][c]
  __shared__ float tbuf[128][128];    // 64 KB per-pair activations (np <= 128)
  __shared__ float esum[2][128];
  __shared__ float prev[128];         // m2[r] + be + bg   (graph_fts == 0)
  __shared__ int p_i[128], p_off[128], p_cnt[128];
  __shared__ int flagscan[128];
  __shared__ int s_np;

  int r = blockIdx.x, tid = threadIdx.x;
  int g = r >> 7;

  int b0 = 0, cc = 0;
  if (tid < 128) {
    b0 = base[r * 128 + tid];
    int b1 = base[r * 128 + tid + 1];
    cc = b1 - b0;
    flagscan[tid] = cc > 0 ? 1 : 0;
    prev[tid] = m2[r * 128 + tid] + be[l * 128 + tid] + bg[l * 128 + tid];
  }
  __syncthreads();
  for (int st = 1; st < 128; st <<= 1) {
    int a = 0, b = 0;
    if (tid < 128) { a = flagscan[tid]; b = (tid >= st) ? flagscan[tid - st] : 0; }
    __syncthreads();
    if (tid < 128) flagscan[tid] = a + b;
    __syncthreads();
  }
  if (tid < 128 && cc > 0) {
    int pos = flagscan[tid] - 1;
    p_i[pos] = tid; p_off[pos] = b0; p_cnt[pos] = cc;
  }
  if (tid == 127) s_np = flagscan[127];
  __syncthreads();
  int np = s_np;
  if (np == 0) {                    // no incoming edges: reference gives NEG
    if (tid < 128) msgs[r * 128 + tid] = NEGV;
    return;
  }
  int half = tid >> 7, t = tid & 127;
  int rounds = (np + 1) >> 1;

  // Phase A: t = relu(m1[i] + m2[r] + edge_sum@We + be + bg)
  for (int idx = tid; idx < 16384; idx += 256) Wlds[idx] = We[l * 16384 + idx];
  __syncthreads();
  for (int ro = 0; ro < rounds; ro++) {
    int p = ro * 2 + half;
    float es = 0.f;
    if (p < np) {
      int off = p_off[p], c = p_cnt[p];
      for (int d2 = 0; d2 < c; d2++) {        // duplicate edges: SUM features
        int eid = sorted_e[off + d2];
        int a0 = edge_attr[eid * 3 + 0];
        int a1 = edge_attr[eid * 3 + 1];
        int a2 = edge_attr[eid * 3 + 2];
        es += bond_emb[a0 * 128 + t] + bond_emb[(16 + a1) * 128 + t] +
              bond_emb[(32 + a2) * 128 + t];
      }
    }
    esum[half][t] = es;
    __syncthreads();
    if (p < np) {
      float acc = 0.f;
#pragma unroll 8
      for (int k = 0; k < 128; k++) acc += esum[half][k] * Wlds[k * 128 + t];
      float m1v = m1[((g << 7) + p_i[p]) * 128 + t];
      tbuf[p][t] = fmaxf(m1v + prev[t] + acc, 0.f);
    }
    __syncthreads();
  }
  // Phase B: u1 = relu(t @ Wp1 + bp1), in-place in tbuf
  for (int idx = tid; idx < 16384; idx += 256) Wlds[idx] = Wp1[l * 16384 + idx];
  __syncthreads();
  for (int ro = 0; ro < rounds; ro++) {
    int p = ro * 2 + half;
    float u = 0.f;
    if (p < np) {
#pragma unroll 8
      for (int k = 0; k < 128; k++) u += tbuf[p][k] * Wlds[k * 128 + t];
      u = fmaxf(u + bp1[l * 128 + t], 0.f);
    }
    __syncthreads();
    if (p < np) tbuf[p][t] = u;
    __syncthreads();
  }
  // Phase C: u2 = u1 @ Wp2 + bp2; running max over senders
  for (int idx = tid; idx < 16384; idx += 256) Wlds[idx] = Wp2[l * 16384 + idx];
  __syncthreads();
  float mymax = NEGV;
  for (int ro = 0; ro < rounds; ro++) {
    int p = ro * 2 + half;
    if (p < np) {
      float u = bp2[l * 128 + t];
#pragma unroll 8
      for (int k = 0; k < 128; k++) u += tbuf[p][k] * Wlds[k * 128 + t];
      mymax = fmaxf(mymax, u);
    }
  }
  __syncthreads();
  esum[half][t] = mymax;
  __syncthreads();
  if (tid < 128) msgs[r * 128 + tid] = fmaxf(esum[0][tid], esum[1][tid]);
}

// ---------------- h = relu(z@Wo1 + bo1 + msgs@Wo2 + bo2); LayerNorm -> hidden
__global__ __launch_bounds__(128) void k_out_ln(const float* __restrict__ nf,
    float* __restrict__ hid, const float* __restrict__ msgs,
    const float* __restrict__ Wo1, const float* __restrict__ bo1,
    const float* __restrict__ Wo2, const float* __restrict__ bo2,
    const float* __restrict__ ln_s, const float* __restrict__ ln_b, int l) {
  __shared__ float zb[8][384];
  __shared__ float hb[8][128];
  __shared__ float mu[8], rs[8];
  int v0 = blockIdx.x * 8, tid = threadIdx.x;
  for (int idx = tid; idx < 8 * 384; idx += 128) {
    int n = idx / 384, c = idx - n * 384;
    float val;
    if (c < 128) val = nf[(v0 + n) * 128 + c];
    else if (c < 256) val = hid[(v0 + n) * 128 + c - 128];
    else val = msgs[(v0 + n) * 128 + c - 256];
    zb[n][c] = val;
  }
  __syncthreads();
  int c = tid;
  float binit = bo1[l * 128 + c] + bo2[l * 128 + c];
  float acc[8];
#pragma unroll
  for (int n = 0; n < 8; n++) acc[n] = binit;
  for (int k = 0; k < 256; k++) {
    float w = Wo1[l * 32768 + k * 128 + c];
#pragma unroll
    for (int n = 0; n < 8; n++) acc[n] += zb[n][k] * w;
  }
  for (int k = 0; k < 128; k++) {
    float w = Wo2[l * 16384 + k * 128 + c];
#pragma unroll
    for (int n = 0; n < 8; n++) acc[n] += zb[n][256 + k] * w;
  }
#pragma unroll
  for (int n = 0; n < 8; n++) hb[n][c] = fmaxf(acc[n], 0.f);
  __syncthreads();
  if (tid < 8) {              // two-pass variance (values can be ~1e9)
    int n = tid; float s = 0.f;
    for (int k = 0; k < 128; k++) s += hb[n][k];
    float m = s * (1.f / 128.f);
    float s2 = 0.f;
    for (int k = 0; k < 128; k++) { float d = hb[n][k] - m; s2 += d * d; }
    mu[n] = m; rs[n] = rsqrtf(s2 * (1.f / 128.f) + 1e-5f);
  }
  __syncthreads();
  float sc = ln_s[l * 128 + c], bb = ln_b[l * 128 + c];
#pragma unroll
  for (int n = 0; n < 8; n++)
    hid[(v0 + n) * 128 + c] = (hb[n][c] - mu[n]) * rs[n] * sc + bb;
}

// ---------------- mean pool over nodes + 2-layer head
__global__ __launch_bounds__(128) void k_head(const float* __restrict__ hid,
    const float* __restrict__ Wh1, const float* __restrict__ bh1,
    const float* __restrict__ Wh2, const float* __restrict__ bh2,
    float* __restrict__ out) {
  __shared__ float ge[128], p1[128];
  int b = blockIdx.x, t = threadIdx.x;
  float s = 0.f;
  for (int n = 0; n < 128; n++) s += hid[(b * 128 + n) * 128 + t];
  ge[t] = s * (1.f / 128.f);
  __syncthreads();
  float a = bh1[t];
  for (int k = 0; k < 128; k++) a += ge[k] * Wh1[k * 128 + t];
  p1[t] = fmaxf(a, 0.f);
  __syncthreads();
  float o = bh2[t];
  for (int k = 0; k < 128; k++) o += p1[k] * Wh2[k * 128 + t];
  out[b * 128 + t] = o;
}

extern "C" void kernel_launch(void* const* d_in, const int* in_sizes, int n_in,
                              void* d_out, int out_size, void* d_ws, size_t ws_size,
                              hipStream_t stream) {
  const int* x          = (const int*)d_in[0];
  const int* edge_attr  = (const int*)d_in[1];
  const int* edge_index = (const int*)d_in[2];
  // d_in[3] batch_idx unused (equal-size graphs)
  const float* atom_emb = (const float*)d_in[4];
  const float* bond_emb = (const float*)d_in[5];
  const float* Wm1 = (const float*)d_in[6];
  const float* bm1 = (const float*)d_in[7];
  const float* Wm2 = (const float*)d_in[8];
  const float* bm2 = (const float*)d_in[9];
  const float* We  = (const float*)d_in[10];
  const float* be  = (const float*)d_in[11];
  // d_in[12] Wg unused: graph_fts is identically zero in the reference
  const float* bg  = (const float*)d_in[13];
  const float* Wp1 = (const float*)d_in[14];
  const float* bp1 = (const float*)d_in[15];
  const float* Wp2 = (const float*)d_in[16];
  const float* bp2 = (const float*)d_in[17];
  const float* Wo1 = (const float*)d_in[18];
  const float* bo1 = (const float*)d_in[19];
  const float* Wo2 = (const float*)d_in[20];
  const float* bo2 = (const float*)d_in[21];
  const float* ln_s = (const float*)d_in[22];
  const float* ln_b = (const float*)d_in[23];
  const float* Wh1 = (const float*)d_in[24];
  const float* bh1 = (const float*)d_in[25];
  const float* Wh2 = (const float*)d_in[26];
  const float* bh2 = (const float*)d_in[27];
  float* out = (float*)d_out;

  // workspace carve-up (~17 MB)
  int* cnt      = (int*)d_ws;                 // 524288
  int* basep    = cnt + SLOTS_;               // 524289 (+pad)
  int* cursor   = basep + (SLOTS_ + 2);       // 524288
  int* bsum     = cursor + SLOTS_;            // 2048
  int* sorted_e = bsum + 2048;                // 65536
  float* node_fts = (float*)(sorted_e + EE_); // 524288 f
  float* hidden   = node_fts + NODES_ * 128;
  float* m1       = hidden + NODES_ * 128;
  float* m2       = m1 + NODES_ * 128;
  float* msgs     = m2 + NODES_ * 128;

  hipMemsetAsync(cnt, 0, SLOTS_ * sizeof(int), stream);
  hipMemsetAsync(hidden, 0, NODES_ * 128 * sizeof(float), stream);

  k_node_enc<<<NODES_, 128, 0, stream>>>(x, atom_emb, node_fts);
  k_edge_count<<<EE_ / 256, 256, 0, stream>>>(edge_index, cnt);
  k_scan1<<<SLOTS_ / 256, 256, 0, stream>>>(cnt, basep, bsum);
  k_scan2<<<1, 256, 0, stream>>>(bsum);
  k_scan3<<<SLOTS_ / 256, 256, 0, stream>>>(basep, cursor, bsum);
  k_edge_scatter<<<EE_ / 256, 256, 0, stream>>>(edge_index, cursor, sorted_e);

  for (int l = 0; l < LL_; l++) {
    k_m12<<<NODES_ / 8, 256, 0, stream>>>(node_fts, hidden, Wm1, bm1, Wm2, bm2,
                                          m1, m2, l);
    k_pairmlp<<<NODES_, 256, 0, stream>>>(m1, m2, basep, sorted_e, edge_attr,
                                          bond_emb, We, be, bg, Wp1, bp1, Wp2,
                                          bp2, msgs, l);
    k_out_ln<<<NODES_ / 8, 128, 0, stream>>>(node_fts, hidden, msgs, Wo1, bo1,
                                             Wo2, bo2, ln_s, ln_b, l);
  }
  k_head<<<NB_, 128, 0, stream>>>(hidden, Wh1, bh1, Wh2, bh2, out);
}

// Round 2
// 587.018 us; speedup vs baseline: 4.3129x; 4.3129x over previous
//
#include <hip/hip_runtime.h>
#include <hip/hip_bf16.h>

#define NB_ 32
#define NN_ 128
#define HH_ 128
#define LL_ 3
#define EE_ 65536
#define NODES_ 4096
#define SLOTS_ 524288   // NODES_ * NN_
#define NEGV -1e9f

// order-preserving float->uint key (max over keys == max over floats)
__device__ __forceinline__ unsigned fkey(float f) {
  unsigned b = __float_as_uint(f);
  unsigned m = ((int)b >> 31) | 0x80000000u;  // neg: 0xFFFFFFFF, pos: 0x80000000
  return b ^ m;
}
__device__ __forceinline__ float funkey(unsigned k) {
  unsigned xm = (k & 0x80000000u) ? 0x80000000u : 0xFFFFFFFFu;
  return __uint_as_float(k ^ xm);
}

// ---------------- node encoder
__global__ __launch_bounds__(128) void k_node_enc(const int* __restrict__ x,
    const float* __restrict__ atom_emb, float* __restrict__ node_fts) {
  int v = blockIdx.x, t = threadIdx.x;
  float acc = 0.f;
#pragma unroll
  for (int c = 0; c < 9; c++) {
    int xv = x[v * 9 + c];
    acc += atom_emb[(c * 128 + xv) * 128 + t];
  }
  node_fts[v * 128 + t] = acc;
}

// ---------------- edge histogram into receiver-major pair slots
__global__ __launch_bounds__(256) void k_edge_count(const int* __restrict__ ei,
                                                    int* __restrict__ cnt) {
  int e = blockIdx.x * 256 + threadIdx.x;
  int s = ei[e], d = ei[EE_ + e];
  int g = s >> 7, i = s & 127, j = d & 127;
  int slot = ((g << 7) + j) * 128 + i;   // receiver-major
  atomicAdd(&cnt[slot], 1);
}

// ---------------- scans (edge offsets + pair-id compaction)
__global__ __launch_bounds__(256) void k_scan1(const int* __restrict__ cnt,
    int* __restrict__ base, int* __restrict__ bsum) {
  __shared__ int s[256];
  int t = threadIdx.x, gid = blockIdx.x * 256 + t;
  int v = cnt[gid];
  s[t] = v; __syncthreads();
  for (int st = 1; st < 256; st <<= 1) {
    int a = s[t]; int b = (t >= st) ? s[t - st] : 0;
    __syncthreads(); s[t] = a + b; __syncthreads();
  }
  base[gid] = s[t] - v;
  if (t == 255) bsum[blockIdx.x] = s[255];
}

__global__ __launch_bounds__(256) void k_scanF1(const int* __restrict__ cnt,
    int* __restrict__ pairbase, int* __restrict__ bsum) {
  __shared__ int s[256];
  int t = threadIdx.x, gid = blockIdx.x * 256 + t;
  int v = cnt[gid] > 0 ? 1 : 0;
  s[t] = v; __syncthreads();
  for (int st = 1; st < 256; st <<= 1) {
    int a = s[t]; int b = (t >= st) ? s[t - st] : 0;
    __syncthreads(); s[t] = a + b; __syncthreads();
  }
  pairbase[gid] = s[t] - v;
  if (t == 255) bsum[blockIdx.x] = s[255];
}

__global__ __launch_bounds__(256) void k_scan2(int* __restrict__ bsum) {
  __shared__ int s[256];
  int t = threadIdx.x;
  int v[8]; int tot = 0;
#pragma unroll
  for (int q = 0; q < 8; q++) { v[q] = bsum[t * 8 + q]; tot += v[q]; }
  s[t] = tot; __syncthreads();
  for (int st = 1; st < 256; st <<= 1) {
    int a = s[t]; int b = (t >= st) ? s[t - st] : 0;
    __syncthreads(); s[t] = a + b; __syncthreads();
  }
  int run = s[t] - tot;
#pragma unroll
  for (int q = 0; q < 8; q++) { int tmp = v[q]; bsum[t * 8 + q] = run; run += tmp; }
}

__global__ __launch_bounds__(256) void k_scan3(int* __restrict__ base,
    int* __restrict__ cursor, const int* __restrict__ bsum) {
  int gid = blockIdx.x * 256 + threadIdx.x;
  int v = base[gid] + bsum[gid >> 8];
  base[gid] = v; cursor[gid] = v;
}

__global__ __launch_bounds__(256) void k_scanF3(int* __restrict__ pairbase,
    const int* __restrict__ cnt, const int* __restrict__ bsum,
    int* __restrict__ pair_total) {
  int gid = blockIdx.x * 256 + threadIdx.x;
  int v = pairbase[gid] + bsum[gid >> 8];
  pairbase[gid] = v;
  if (gid == SLOTS_ - 1) pair_total[0] = v + (cnt[gid] > 0 ? 1 : 0);
}

// ---------------- scatter edge ids into receiver-major sorted order
__global__ __launch_bounds__(256) void k_edge_scatter(const int* __restrict__ ei,
    int* __restrict__ cursor, int* __restrict__ sorted_e) {
  int e = blockIdx.x * 256 + threadIdx.x;
  int s = ei[e], d = ei[EE_ + e];
  int g = s >> 7, i = s & 127, j = d & 127;
  int slot = ((g << 7) + j) * 128 + i;
  int pos = atomicAdd(&cursor[slot], 1);
  sorted_e[pos] = e;
}

// ---------------- build compact pair arrays
__global__ __launch_bounds__(256) void k_pair_build(const int* __restrict__ cnt,
    const int* __restrict__ basep, const int* __restrict__ pairbase,
    int* __restrict__ pair_slot, int* __restrict__ pair_off,
    int* __restrict__ pair_cnt) {
  int s = blockIdx.x * 256 + threadIdx.x;
  int c = cnt[s];
  if (c > 0) {
    int pid = pairbase[s];
    pair_slot[pid] = s;
    pair_off[pid] = basep[s];
    pair_cnt[pid] = c;
  }
}

// ---------------- msgs init (transformed NEG)
__global__ __launch_bounds__(256) void k_msgs_init(unsigned* __restrict__ msgs_u) {
  int i = blockIdx.x * 256 + threadIdx.x;
  msgs_u[i] = fkey(NEGV);
}

// ---------------- bembWe[l] = bond_emb @ We[l]  ([48,128]x[128,128])
__global__ __launch_bounds__(128) void k_bembWe(const float* __restrict__ bond_emb,
    const float* __restrict__ We, float* __restrict__ bembWe, int l) {
  __shared__ float row[128];
  int rr = blockIdx.x, c = threadIdx.x;
  row[c] = bond_emb[rr * 128 + c];
  __syncthreads();
  const float* W = We + l * 16384;
  float acc = 0.f;
  for (int k = 0; k < 128; k += 4) {
    acc += row[k] * W[k * 128 + c] + row[k + 1] * W[(k + 1) * 128 + c] +
           row[k + 2] * W[(k + 2) * 128 + c] + row[k + 3] * W[(k + 3) * 128 + c];
  }
  bembWe[rr * 128 + c] = acc;
}

// ---------------- m1/m2: [4096,256]@[256,128] x2, 8 nodes/block
__global__ __launch_bounds__(256) void k_m12(const float* __restrict__ nf,
    const float* __restrict__ hid,
    const float* __restrict__ Wm1, const float* __restrict__ bm1,
    const float* __restrict__ Wm2, const float* __restrict__ bm2,
    float* __restrict__ m1, float* __restrict__ m2, int l) {
  __shared__ float zb[8][256];
  int v0 = blockIdx.x * 8, tid = threadIdx.x;
#pragma unroll
  for (int n = 0; n < 8; n++)
    zb[n][tid] = (tid < 128) ? nf[(v0 + n) * 128 + tid]
                             : hid[(v0 + n) * 128 + (tid - 128)];
  __syncthreads();
  int hs = tid >> 7, c = tid & 127;
  const float* W = (hs ? Wm2 : Wm1) + l * 32768;
  float bv = (hs ? bm2 : bm1)[l * 128 + c];
  float acc[8];
#pragma unroll
  for (int n = 0; n < 8; n++) acc[n] = bv;
  for (int k = 0; k < 256; k += 4) {
    float w0 = W[k * 128 + c], w1 = W[(k + 1) * 128 + c];
    float w2 = W[(k + 2) * 128 + c], w3 = W[(k + 3) * 128 + c];
#pragma unroll
    for (int n = 0; n < 8; n++) {
      float4 z4 = *(const float4*)&zb[n][k];
      acc[n] += z4.x * w0 + z4.y * w1 + z4.z * w2 + z4.w * w3;
    }
  }
  float* out = hs ? m2 : m1;
#pragma unroll
  for (int n = 0; n < 8; n++) out[(v0 + n) * 128 + c] = acc[n];
}

// ---------------- fused pair MLP over flattened pair list + seg-max
__global__ __launch_bounds__(256, 4) void k_pairs(
    const float* __restrict__ m1, const float* __restrict__ m2,
    const int* __restrict__ pair_slot, const int* __restrict__ pair_off,
    const int* __restrict__ pair_cnt, const int* __restrict__ pair_total,
    const int* __restrict__ sorted_e, const int* __restrict__ edge_attr,
    const float* __restrict__ bembWe,
    const float* __restrict__ be, const float* __restrict__ bg,
    const float* __restrict__ Wp1, const float* __restrict__ bp1,
    const float* __restrict__ Wp2, const float* __restrict__ bp2,
    unsigned* __restrict__ msgs_u, int l) {
  __shared__ float Tt[16][128];
  __shared__ float Ut[16][128];
  __shared__ int s_slot[16], s_off[16], s_cnt[16];
  int P = pair_total[0];
  int pid0 = blockIdx.x * 16;
  if (pid0 >= P) return;
  int tid = threadIdx.x;
  if (tid < 16) {
    int pid = pid0 + tid;
    bool val = pid < P;
    s_slot[tid] = val ? pair_slot[pid] : -1;
    s_off[tid] = val ? pair_off[pid] : 0;
    s_cnt[tid] = val ? pair_cnt[pid] : 0;
  }
  __syncthreads();
  // ---- phase 0: T = relu(m1[i] + m2[r] + be + bg + sum_dups bembWe rows)
  {
    int p = tid >> 4;            // 0..15
    int c0 = (tid & 15) * 8;
    int slot = s_slot[p];
    if (slot >= 0) {
      int r = slot >> 7, i = slot & 127, g = slot >> 14;
      int sn = (g << 7) + i;
      const float4* m1p = (const float4*)(m1 + sn * 128 + c0);
      const float4* m2p = (const float4*)(m2 + r * 128 + c0);
      const float4* bep = (const float4*)(be + l * 128 + c0);
      const float4* bgp = (const float4*)(bg + l * 128 + c0);
      float4 aL, aH;
      {
        float4 x0 = m1p[0], x1 = m2p[0], x2 = bep[0], x3 = bgp[0];
        aL.x = x0.x + x1.x + x2.x + x3.x; aL.y = x0.y + x1.y + x2.y + x3.y;
        aL.z = x0.z + x1.z + x2.z + x3.z; aL.w = x0.w + x1.w + x2.w + x3.w;
        x0 = m1p[1]; x1 = m2p[1]; x2 = bep[1]; x3 = bgp[1];
        aH.x = x0.x + x1.x + x2.x + x3.x; aH.y = x0.y + x1.y + x2.y + x3.y;
        aH.z = x0.z + x1.z + x2.z + x3.z; aH.w = x0.w + x1.w + x2.w + x3.w;
      }
      int off = s_off[p], cn = s_cnt[p];
      for (int d = 0; d < cn; d++) {
        int eid = sorted_e[off + d];
        int a0 = edge_attr[eid * 3], a1 = edge_attr[eid * 3 + 1],
            a2 = edge_attr[eid * 3 + 2];
        const float4* r0 = (const float4*)(bembWe + a0 * 128 + c0);
        const float4* r1 = (const float4*)(bembWe + (16 + a1) * 128 + c0);
        const float4* r2 = (const float4*)(bembWe + (32 + a2) * 128 + c0);
        float4 y0 = r0[0], y1 = r1[0], y2 = r2[0];
        aL.x += y0.x + y1.x + y2.x; aL.y += y0.y + y1.y + y2.y;
        aL.z += y0.z + y1.z + y2.z; aL.w += y0.w + y1.w + y2.w;
        y0 = r0[1]; y1 = r1[1]; y2 = r2[1];
        aH.x += y0.x + y1.x + y2.x; aH.y += y0.y + y1.y + y2.y;
        aH.z += y0.z + y1.z + y2.z; aH.w += y0.w + y1.w + y2.w;
      }
      float4* trow = (float4*)&Tt[p][c0];
      trow[0] = make_float4(fmaxf(aL.x, 0.f), fmaxf(aL.y, 0.f),
                            fmaxf(aL.z, 0.f), fmaxf(aL.w, 0.f));
      trow[1] = make_float4(fmaxf(aH.x, 0.f), fmaxf(aH.y, 0.f),
                            fmaxf(aH.z, 0.f), fmaxf(aH.w, 0.f));
    } else {
      float4* trow = (float4*)&Tt[p][c0];
      trow[0] = make_float4(0.f, 0.f, 0.f, 0.f);
      trow[1] = make_float4(0.f, 0.f, 0.f, 0.f);
    }
  }
  __syncthreads();
  int c = tid & 127, half = tid >> 7;
  // ---- phase 1: U = relu(T @ Wp1 + bp1)
  {
    const float* W = Wp1 + l * 16384;
    float acc[8];
#pragma unroll
    for (int j = 0; j < 8; j++) acc[j] = 0.f;
    for (int k = 0; k < 128; k += 4) {
      float w0 = W[k * 128 + c], w1 = W[(k + 1) * 128 + c];
      float w2 = W[(k + 2) * 128 + c], w3 = W[(k + 3) * 128 + c];
#pragma unroll
      for (int j = 0; j < 8; j++) {
        float4 t4 = *(const float4*)&Tt[half * 8 + j][k];
        acc[j] += t4.x * w0 + t4.y * w1 + t4.z * w2 + t4.w * w3;
      }
    }
    float b1 = bp1[l * 128 + c];
#pragma unroll
    for (int j = 0; j < 8; j++) Ut[half * 8 + j][c] = fmaxf(acc[j] + b1, 0.f);
  }
  __syncthreads();
  // ---- phase 2: V = U @ Wp2 + bp2 ; run-merged atomic seg-max
  {
    const float* W = Wp2 + l * 16384;
    float acc[8];
#pragma unroll
    for (int j = 0; j < 8; j++) acc[j] = 0.f;
    for (int k = 0; k < 128; k += 4) {
      float w0 = W[k * 128 + c], w1 = W[(k + 1) * 128 + c];
      float w2 = W[(k + 2) * 128 + c], w3 = W[(k + 3) * 128 + c];
#pragma unroll
      for (int j = 0; j < 8; j++) {
        float4 u4 = *(const float4*)&Ut[half * 8 + j][k];
        acc[j] += u4.x * w0 + u4.y * w1 + u4.z * w2 + u4.w * w3;
      }
    }
    float b2 = bp2[l * 128 + c];
    int prev_r = -1; float run = 0.f;
#pragma unroll
    for (int j = 0; j < 8; j++) {
      int slot = s_slot[half * 8 + j];
      if (slot < 0) continue;
      int r = slot >> 7;
      float v = acc[j] + b2;
      if (r == prev_r) {
        run = fmaxf(run, v);
      } else {
        if (prev_r >= 0) atomicMax(&msgs_u[prev_r * 128 + c], fkey(run));
        prev_r = r; run = v;
      }
    }
    if (prev_r >= 0) atomicMax(&msgs_u[prev_r * 128 + c], fkey(run));
  }
}

// ---------------- h = relu(z@Wo1 + msgs@Wo2 + b); LayerNorm -> hidden
__global__ __launch_bounds__(256) void k_out_ln(const float* __restrict__ nf,
    float* __restrict__ hid, const unsigned* __restrict__ msgs_u,
    const float* __restrict__ Wo1, const float* __restrict__ bo1,
    const float* __restrict__ Wo2, const float* __restrict__ bo2,
    const float* __restrict__ ln_s, const float* __restrict__ ln_b, int l) {
  __shared__ float zb[8][256];
  __shared__ float mb[8][128];
  __shared__ float hb[8][128];
  __shared__ float mu[8], rs[8];
  int v0 = blockIdx.x * 8, tid = threadIdx.x;
  for (int idx = tid; idx < 2048; idx += 256) {
    int n = idx >> 8, cc = idx & 255;
    zb[n][cc] = (cc < 128) ? nf[(v0 + n) * 128 + cc]
                           : hid[(v0 + n) * 128 + (cc - 128)];
  }
  for (int idx = tid; idx < 1024; idx += 256) {
    int n = idx >> 7, cc = idx & 127;
    mb[n][cc] = funkey(msgs_u[(v0 + n) * 128 + cc]);
  }
  __syncthreads();
  int c = tid & 127, ng = tid >> 7;
  float binit = bo1[l * 128 + c] + bo2[l * 128 + c];
  float acc[4];
#pragma unroll
  for (int q = 0; q < 4; q++) acc[q] = binit;
  const float* W1 = Wo1 + l * 32768;
  for (int k = 0; k < 256; k += 4) {
    float w0 = W1[k * 128 + c], w1 = W1[(k + 1) * 128 + c];
    float w2 = W1[(k + 2) * 128 + c], w3 = W1[(k + 3) * 128 + c];
#pragma unroll
    for (int q = 0; q < 4; q++) {
      float4 z4 = *(const float4*)&zb[ng * 4 + q][k];
      acc[q] += z4.x * w0 + z4.y * w1 + z4.z * w2 + z4.w * w3;
    }
  }
  const float* W2 = Wo2 + l * 16384;
  for (int k = 0; k < 128; k += 4) {
    float w0 = W2[k * 128 + c], w1 = W2[(k + 1) * 128 + c];
    float w2 = W2[(k + 2) * 128 + c], w3 = W2[(k + 3) * 128 + c];
#pragma unroll
    for (int q = 0; q < 4; q++) {
      float4 m4 = *(const float4*)&mb[ng * 4 + q][k];
      acc[q] += m4.x * w0 + m4.y * w1 + m4.z * w2 + m4.w * w3;
    }
  }
#pragma unroll
  for (int q = 0; q < 4; q++) hb[ng * 4 + q][c] = fmaxf(acc[q], 0.f);
  __syncthreads();
  {
    int n = tid >> 5, l32 = tid & 31;
    float s = hb[n][l32] + hb[n][l32 + 32] + hb[n][l32 + 64] + hb[n][l32 + 96];
#pragma unroll
    for (int m = 16; m >= 1; m >>= 1) s += __shfl_xor(s, m, 64);
    if (l32 == 0) mu[n] = s * (1.f / 128.f);
  }
  __syncthreads();
  {
    int n = tid >> 5, l32 = tid & 31;
    float m = mu[n];
    float d0 = hb[n][l32] - m, d1 = hb[n][l32 + 32] - m;
    float d2 = hb[n][l32 + 64] - m, d3 = hb[n][l32 + 96] - m;
    float s = d0 * d0 + d1 * d1 + d2 * d2 + d3 * d3;
#pragma unroll
    for (int m2 = 16; m2 >= 1; m2 >>= 1) s += __shfl_xor(s, m2, 64);
    if (l32 == 0) rs[n] = rsqrtf(s * (1.f / 128.f) + 1e-5f);
  }
  __syncthreads();
  float sc = ln_s[l * 128 + c], bb = ln_b[l * 128 + c];
#pragma unroll
  for (int q = 0; q < 4; q++) {
    int n = ng * 4 + q;
    hid[(v0 + n) * 128 + c] = (hb[n][c] - mu[n]) * rs[n] * sc + bb;
  }
}

// ---------------- mean pool over nodes + 2-layer head
__global__ __launch_bounds__(128) void k_head(const float* __restrict__ hid,
    const float* __restrict__ Wh1, const float* __restrict__ bh1,
    const float* __restrict__ Wh2, const float* __restrict__ bh2,
    float* __restrict__ out) {
  __shared__ float ge[128], p1[128];
  int b = blockIdx.x, t = threadIdx.x;
  float s = 0.f;
  for (int n = 0; n < 128; n++) s += hid[(b * 128 + n) * 128 + t];
  ge[t] = s * (1.f / 128.f);
  __syncthreads();
  float a = bh1[t];
  for (int k = 0; k < 128; k++) a += ge[k] * Wh1[k * 128 + t];
  p1[t] = fmaxf(a, 0.f);
  __syncthreads();
  float o = bh2[t];
  for (int k = 0; k < 128; k++) o += p1[k] * Wh2[k * 128 + t];
  out[b * 128 + t] = o;
}

extern "C" void kernel_launch(void* const* d_in, const int* in_sizes, int n_in,
                              void* d_out, int out_size, void* d_ws, size_t ws_size,
                              hipStream_t stream) {
  const int* x          = (const int*)d_in[0];
  const int* edge_attr  = (const int*)d_in[1];
  const int* edge_index = (const int*)d_in[2];
  const float* atom_emb = (const float*)d_in[4];
  const float* bond_emb = (const float*)d_in[5];
  const float* Wm1 = (const float*)d_in[6];
  const float* bm1 = (const float*)d_in[7];
  const float* Wm2 = (const float*)d_in[8];
  const float* bm2 = (const float*)d_in[9];
  const float* We  = (const float*)d_in[10];
  const float* be  = (const float*)d_in[11];
  const float* bg  = (const float*)d_in[13];   // Wg dead: graph_fts == 0
  const float* Wp1 = (const float*)d_in[14];
  const float* bp1 = (const float*)d_in[15];
  const float* Wp2 = (const float*)d_in[16];
  const float* bp2 = (const float*)d_in[17];
  const float* Wo1 = (const float*)d_in[18];
  const float* bo1 = (const float*)d_in[19];
  const float* Wo2 = (const float*)d_in[20];
  const float* bo2 = (const float*)d_in[21];
  const float* ln_s = (const float*)d_in[22];
  const float* ln_b = (const float*)d_in[23];
  const float* Wh1 = (const float*)d_in[24];
  const float* bh1 = (const float*)d_in[25];
  const float* Wh2 = (const float*)d_in[26];
  const float* bh2 = (const float*)d_in[27];
  float* out = (float*)d_out;

  // workspace carve-up (~16 MB)
  int* cnt       = (int*)d_ws;                  // 524288
  int* basep     = cnt + SLOTS_;                // 524288
  int* cursor    = basep + SLOTS_;              // 524288
  int* pairbase  = cursor + SLOTS_;             // 524288
  int* bsumA     = pairbase + SLOTS_;           // 2048
  int* bsumF     = bsumA + 2048;                // 2048
  int* pair_tot  = bsumF + 2048;                // 16
  int* sorted_e  = pair_tot + 16;               // 65536
  int* pair_slot = sorted_e + EE_;              // 65536
  int* pair_off  = pair_slot + EE_;             // 65536
  int* pair_cnt  = pair_off + EE_;              // 65536
  float* node_fts = (float*)(pair_cnt + EE_);   // 524288 f
  float* hidden   = node_fts + SLOTS_;          // 524288 f
  float* m1       = hidden + SLOTS_;            // 524288 f
  float* m2       = m1 + SLOTS_;                // 524288 f
  unsigned* msgs_u = (unsigned*)(m2 + SLOTS_);  // 524288 u
  float* bembWe   = (float*)(msgs_u + SLOTS_);  // 6144 f

  hipMemsetAsync(cnt, 0, SLOTS_ * sizeof(int), stream);
  hipMemsetAsync(hidden, 0, SLOTS_ * sizeof(float), stream);

  k_node_enc<<<NODES_, 128, 0, stream>>>(x, atom_emb, node_fts);
  k_edge_count<<<EE_ / 256, 256, 0, stream>>>(edge_index, cnt);
  k_scan1<<<SLOTS_ / 256, 256, 0, stream>>>(cnt, basep, bsumA);
  k_scan2<<<1, 256, 0, stream>>>(bsumA);
  k_scan3<<<SLOTS_ / 256, 256, 0, stream>>>(basep, cursor, bsumA);
  k_edge_scatter<<<EE_ / 256, 256, 0, stream>>>(edge_index, cursor, sorted_e);
  k_scanF1<<<SLOTS_ / 256, 256, 0, stream>>>(cnt, pairbase, bsumF);
  k_scan2<<<1, 256, 0, stream>>>(bsumF);
  k_scanF3<<<SLOTS_ / 256, 256, 0, stream>>>(pairbase, cnt, bsumF, pair_tot);
  k_pair_build<<<SLOTS_ / 256, 256, 0, stream>>>(cnt, basep, pairbase,
                                                 pair_slot, pair_off, pair_cnt);

  for (int l = 0; l < LL_; l++) {
    k_m12<<<NODES_ / 8, 256, 0, stream>>>(node_fts, hidden, Wm1, bm1, Wm2, bm2,
                                          m1, m2, l);
    k_bembWe<<<48, 128, 0, stream>>>(bond_emb, We, bembWe, l);
    k_msgs_init<<<SLOTS_ / 256, 256, 0, stream>>>(msgs_u);
    k_pairs<<<EE_ / 16, 256, 0, stream>>>(m1, m2, pair_slot, pair_off, pair_cnt,
                                          pair_tot, sorted_e, edge_attr, bembWe,
                                          be, bg, Wp1, bp1, Wp2, bp2, msgs_u, l);
    k_out_ln<<<NODES_ / 8, 256, 0, stream>>>(node_fts, hidden, msgs_u, Wo1, bo1,
                                             Wo2, bo2, ln_s, ln_b, l);
  }
  k_head<<<NB_, 128, 0, stream>>>(hidden, Wh1, bh1, Wh2, bh2, out);
}

// Round 3
// 441.938 us; speedup vs baseline: 5.7288x; 1.3283x over previous
//
#include <hip/hip_runtime.h>
#include <hip/hip_bf16.h>

#define NB_ 32
#define LL_ 3
#define EE_ 65536
#define NODES_ 4096
#define SLOTS_ 524288   // NODES_ * 128
#define NEGV -1e9f

typedef _Float16 f16x8 __attribute__((ext_vector_type(8)));
typedef float f32x4 __attribute__((ext_vector_type(4)));

// order-preserving float->uint key (max over keys == max over floats)
__device__ __forceinline__ unsigned fkey(float f) {
  unsigned b = __float_as_uint(f);
  unsigned m = ((int)b >> 31) | 0x80000000u;
  return b ^ m;
}
__device__ __forceinline__ float funkey(unsigned k) {
  unsigned xm = (k & 0x80000000u) ? 0x80000000u : 0xFFFFFFFFu;
  return __uint_as_float(k ^ xm);
}

// ---------------- node encoder
__global__ __launch_bounds__(128) void k_node_enc(const int* __restrict__ x,
    const float* __restrict__ atom_emb, float* __restrict__ node_fts) {
  int v = blockIdx.x, t = threadIdx.x;
  float acc = 0.f;
#pragma unroll
  for (int c = 0; c < 9; c++) {
    int xv = x[v * 9 + c];
    acc += atom_emb[(c * 128 + xv) * 128 + t];
  }
  node_fts[v * 128 + t] = acc;
}

// ---------------- edge histogram into receiver-major pair slots
__global__ __launch_bounds__(256) void k_edge_count(const int* __restrict__ ei,
                                                    int* __restrict__ cnt) {
  int e = blockIdx.x * 256 + threadIdx.x;
  int s = ei[e], d = ei[EE_ + e];
  int g = s >> 7, i = s & 127, j = d & 127;
  int slot = ((g << 7) + j) * 128 + i;   // receiver-major
  atomicAdd(&cnt[slot], 1);
}

// ---------------- fused block-scan: edge-count scan + pair-flag scan
__global__ __launch_bounds__(256) void k_scanA(const int* __restrict__ cnt,
    int* __restrict__ base, int* __restrict__ pairbase,
    int* __restrict__ bsumA, int* __restrict__ bsumF) {
  __shared__ int sA[256], sF[256];
  int t = threadIdx.x, gid = blockIdx.x * 256 + t;
  int v = cnt[gid];
  int f = v > 0 ? 1 : 0;
  sA[t] = v; sF[t] = f; __syncthreads();
  for (int st = 1; st < 256; st <<= 1) {
    int aA = sA[t], aF = sF[t];
    int bA = (t >= st) ? sA[t - st] : 0;
    int bF = (t >= st) ? sF[t - st] : 0;
    __syncthreads();
    sA[t] = aA + bA; sF[t] = aF + bF;
    __syncthreads();
  }
  base[gid] = sA[t] - v;
  pairbase[gid] = sF[t] - f;
  if (t == 255) { bsumA[blockIdx.x] = sA[255]; bsumF[blockIdx.x] = sF[255]; }
}

// ---------------- scan of the 2048 block sums (block 0: A, block 1: F)
__global__ __launch_bounds__(256) void k_scan2d(int* __restrict__ bsumA,
                                                int* __restrict__ bsumF) {
  int* bsum = blockIdx.x ? bsumF : bsumA;
  __shared__ int s[256];
  int t = threadIdx.x;
  int v[8]; int tot = 0;
#pragma unroll
  for (int q = 0; q < 8; q++) { v[q] = bsum[t * 8 + q]; tot += v[q]; }
  s[t] = tot; __syncthreads();
  for (int st = 1; st < 256; st <<= 1) {
    int a = s[t]; int b = (t >= st) ? s[t - st] : 0;
    __syncthreads(); s[t] = a + b; __syncthreads();
  }
  int run = s[t] - tot;
#pragma unroll
  for (int q = 0; q < 8; q++) { int tmp = v[q]; bsum[t * 8 + q] = run; run += tmp; }
}

// ---------------- finalize scans + build compact pair arrays
__global__ __launch_bounds__(256) void k_scanB(const int* __restrict__ cnt,
    int* __restrict__ base, const int* __restrict__ pairbase,
    int* __restrict__ cursor, const int* __restrict__ bsumA,
    const int* __restrict__ bsumF, int* __restrict__ pair_total,
    int* __restrict__ pair_slot, int* __restrict__ pair_off,
    int* __restrict__ pair_cnt) {
  int gid = blockIdx.x * 256 + threadIdx.x;
  int b = base[gid] + bsumA[gid >> 8];
  int pb = pairbase[gid] + bsumF[gid >> 8];
  base[gid] = b; cursor[gid] = b;
  int c = cnt[gid];
  if (c > 0) {
    pair_slot[pb] = gid;
    pair_off[pb] = b;
    pair_cnt[pb] = c;
  }
  if (gid == SLOTS_ - 1) pair_total[0] = pb + (c > 0 ? 1 : 0);
}

// ---------------- scatter edge ids into receiver-major sorted order
__global__ __launch_bounds__(256) void k_edge_scatter(const int* __restrict__ ei,
    int* __restrict__ cursor, int* __restrict__ sorted_e) {
  int e = blockIdx.x * 256 + threadIdx.x;
  int s = ei[e], d = ei[EE_ + e];
  int g = s >> 7, i = s & 127, j = d & 127;
  int slot = ((g << 7) + j) * 128 + i;
  int pos = atomicAdd(&cursor[slot], 1);
  sorted_e[pos] = e;
}

// ---------------- weight prep: Wp1/Wp2 (3 layers) -> fp16 fragment-major
// frag layout: Wh[mat][(ct*4+kt)*64 + lane][e] ; B-frag: col=lane&15, k=(lane>>4)*8+e
__global__ __launch_bounds__(256) void k_wprep(const float* __restrict__ Wp1,
    const float* __restrict__ Wp2, _Float16* __restrict__ Wh) {
  int gid = blockIdx.x * 256 + threadIdx.x;   // 0..12287
  int mat = gid >> 11;                        // 0..5 = (layer, which)
  int pos = gid & 2047;                       // (ct*4+kt)*64 + lane
  int lane = pos & 63, fr = pos >> 6;
  int ct = fr >> 2, kt = fr & 3;
  int lyr = mat >> 1, which = mat & 1;
  const float* W = (which ? Wp2 : Wp1) + lyr * 16384;
  int col = ct * 16 + (lane & 15);
  int kbase = kt * 32 + (lane >> 4) * 8;
  f16x8 h;
#pragma unroll
  for (int e = 0; e < 8; e++) h[e] = (_Float16)W[(kbase + e) * 128 + col];
  ((f16x8*)Wh)[gid] = h;
}

// ---------------- bembWe[l] = bond_emb @ We[l]  ([48,128]x[128,128])
__global__ __launch_bounds__(128) void k_bembWe(const float* __restrict__ bond_emb,
    const float* __restrict__ We, float* __restrict__ bembWe, int l) {
  __shared__ float row[128];
  int rr = blockIdx.x, c = threadIdx.x;
  row[c] = bond_emb[rr * 128 + c];
  __syncthreads();
  const float* W = We + l * 16384;
  float acc = 0.f;
  for (int k = 0; k < 128; k += 4) {
    acc += row[k] * W[k * 128 + c] + row[k + 1] * W[(k + 1) * 128 + c] +
           row[k + 2] * W[(k + 2) * 128 + c] + row[k + 3] * W[(k + 3) * 128 + c];
  }
  bembWe[rr * 128 + c] = acc;
}

// ---------------- m1/m2 GEMMs + msgs re-init fused
__global__ __launch_bounds__(256) void k_m12(const float* __restrict__ nf,
    const float* __restrict__ hid,
    const float* __restrict__ Wm1, const float* __restrict__ bm1,
    const float* __restrict__ Wm2, const float* __restrict__ bm2,
    float* __restrict__ m1, float* __restrict__ m2,
    unsigned* __restrict__ msgs_u, int l) {
  int tid = threadIdx.x;
  {  // fused msgs init: 512 blocks * 256 thr * 4 = 524288
    int g0 = blockIdx.x * 256 + tid;
    unsigned kneg = fkey(NEGV);
    msgs_u[g0] = kneg;
    msgs_u[g0 + 131072] = kneg;
    msgs_u[g0 + 262144] = kneg;
    msgs_u[g0 + 393216] = kneg;
  }
  __shared__ float zb[8][256];
  int v0 = blockIdx.x * 8;
#pragma unroll
  for (int n = 0; n < 8; n++)
    zb[n][tid] = (tid < 128) ? nf[(v0 + n) * 128 + tid]
                             : hid[(v0 + n) * 128 + (tid - 128)];
  __syncthreads();
  int hs = tid >> 7, c = tid & 127;
  const float* W = (hs ? Wm2 : Wm1) + l * 32768;
  float bv = (hs ? bm2 : bm1)[l * 128 + c];
  float acc[8];
#pragma unroll
  for (int n = 0; n < 8; n++) acc[n] = bv;
  for (int k = 0; k < 256; k += 4) {
    float w0 = W[k * 128 + c], w1 = W[(k + 1) * 128 + c];
    float w2 = W[(k + 2) * 128 + c], w3 = W[(k + 3) * 128 + c];
#pragma unroll
    for (int n = 0; n < 8; n++) {
      float4 z4 = *(const float4*)&zb[n][k];
      acc[n] += z4.x * w0 + z4.y * w1 + z4.z * w2 + z4.w * w3;
    }
  }
  float* out = hs ? m2 : m1;
#pragma unroll
  for (int n = 0; n < 8; n++) out[(v0 + n) * 128 + c] = acc[n];
}

// ---------------- MFMA pair MLP: 64 pairs/block, fp16 in / fp32 accum
__global__ __launch_bounds__(256, 3) void k_pairs(
    const float* __restrict__ m1, const float* __restrict__ m2,
    const int* __restrict__ pair_slot, const int* __restrict__ pair_off,
    const int* __restrict__ pair_cnt, const int* __restrict__ pair_total,
    const int* __restrict__ sorted_e, const int* __restrict__ edge_attr,
    const float* __restrict__ bembWe,
    const float* __restrict__ be, const float* __restrict__ bg,
    const _Float16* __restrict__ Wh,
    const float* __restrict__ bp1, const float* __restrict__ bp2,
    unsigned* __restrict__ msgs_u, int l) {
  __shared__ f16x8 Tf[16][64];      // A-frag-ordered T: [w*4+kt][lane], 16 KB
  __shared__ float Ul[64 * 128];    // U row-major fp32, XOR-swizzled, 32 KB
  __shared__ int s_slot[64], s_off[64], s_cnt[64];
  __shared__ float b1s[128], b2s[128];
  int P = pair_total[0];
  int pid0 = blockIdx.x * 64;
  if (pid0 >= P) return;
  int tid = threadIdx.x;
  if (tid < 64) {
    int pid = pid0 + tid;
    bool va = pid < P;
    s_slot[tid] = va ? pair_slot[pid] : -1;
    s_off[tid] = va ? pair_off[pid] : 0;
    s_cnt[tid] = va ? pair_cnt[pid] : 0;
  } else if (tid < 192) {
    int c = tid - 64;
    b1s[c] = bp1[l * 128 + c];
    b2s[c] = bp2[l * 128 + c];
  }
  __syncthreads();
  // ---- phase 0: T = relu(m1[i]+m2[r]+be+bg+sum_dups bembWe) -> A-frag LDS
  {
    int p = tid & 63, m = tid >> 6;
    int slot = s_slot[p];
    int w0 = p >> 4, ll = p & 15;
    int off = s_off[p], cn = s_cnt[p];
    int rr = slot >> 7, i = slot & 127, g = slot >> 14;
    int sn = (g << 7) + i;
#pragma unroll
    for (int r = 0; r < 4; r++) {
      int chunk = m + 4 * r;      // 0..15
      int c0 = chunk * 8;
      f16x8 h;
      if (slot >= 0) {
        const float4* m1p = (const float4*)(m1 + sn * 128 + c0);
        const float4* m2p = (const float4*)(m2 + rr * 128 + c0);
        const float4* bep = (const float4*)(be + l * 128 + c0);
        const float4* bgp = (const float4*)(bg + l * 128 + c0);
        float4 aL, aH;
        {
          float4 x0 = m1p[0], x1 = m2p[0], x2 = bep[0], x3 = bgp[0];
          aL.x = x0.x + x1.x + x2.x + x3.x; aL.y = x0.y + x1.y + x2.y + x3.y;
          aL.z = x0.z + x1.z + x2.z + x3.z; aL.w = x0.w + x1.w + x2.w + x3.w;
          x0 = m1p[1]; x1 = m2p[1]; x2 = bep[1]; x3 = bgp[1];
          aH.x = x0.x + x1.x + x2.x + x3.x; aH.y = x0.y + x1.y + x2.y + x3.y;
          aH.z = x0.z + x1.z + x2.z + x3.z; aH.w = x0.w + x1.w + x2.w + x3.w;
        }
        for (int d = 0; d < cn; d++) {
          int eid = sorted_e[off + d];
          int a0 = edge_attr[eid * 3], a1 = edge_attr[eid * 3 + 1],
              a2 = edge_attr[eid * 3 + 2];
          const float4* r0 = (const float4*)(bembWe + a0 * 128 + c0);
          const float4* r1 = (const float4*)(bembWe + (16 + a1) * 128 + c0);
          const float4* r2 = (const float4*)(bembWe + (32 + a2) * 128 + c0);
          float4 y0 = r0[0], y1 = r1[0], y2 = r2[0];
          aL.x += y0.x + y1.x + y2.x; aL.y += y0.y + y1.y + y2.y;
          aL.z += y0.z + y1.z + y2.z; aL.w += y0.w + y1.w + y2.w;
          y0 = r0[1]; y1 = r1[1]; y2 = r2[1];
          aH.x += y0.x + y1.x + y2.x; aH.y += y0.y + y1.y + y2.y;
          aH.z += y0.z + y1.z + y2.z; aH.w += y0.w + y1.w + y2.w;
        }
        h[0] = (_Float16)fmaxf(aL.x, 0.f); h[1] = (_Float16)fmaxf(aL.y, 0.f);
        h[2] = (_Float16)fmaxf(aL.z, 0.f); h[3] = (_Float16)fmaxf(aL.w, 0.f);
        h[4] = (_Float16)fmaxf(aH.x, 0.f); h[5] = (_Float16)fmaxf(aH.y, 0.f);
        h[6] = (_Float16)fmaxf(aH.z, 0.f); h[7] = (_Float16)fmaxf(aH.w, 0.f);
      } else {
#pragma unroll
        for (int e = 0; e < 8; e++) h[e] = (_Float16)0.f;
      }
      Tf[w0 * 4 + (chunk >> 2)][ll | ((chunk & 3) << 4)] = h;
    }
  }
  __syncthreads();
  int l64 = tid & 63, wv = tid >> 6;
  int llo = l64 & 15, lhi = l64 >> 4;
  const f16x8* W1f = (const f16x8*)(Wh + (size_t)(l * 2) * 16384);
  const f16x8* W2f = (const f16x8*)(Wh + (size_t)(l * 2 + 1) * 16384);
  // ---- phase 1: U = relu(T @ Wp1 + bp1) -> swizzled LDS
  {
    f16x8 a0 = Tf[wv * 4 + 0][l64];
    f16x8 a1 = Tf[wv * 4 + 1][l64];
    f16x8 a2 = Tf[wv * 4 + 2][l64];
    f16x8 a3 = Tf[wv * 4 + 3][l64];
#pragma unroll
    for (int ct = 0; ct < 8; ct++) {
      int col = ct * 16 + llo;
      float b1 = b1s[col];
      f32x4 acc = {b1, b1, b1, b1};
      acc = __builtin_amdgcn_mfma_f32_16x16x32_f16(a0, W1f[(ct * 4 + 0) * 64 + l64], acc, 0, 0, 0);
      acc = __builtin_amdgcn_mfma_f32_16x16x32_f16(a1, W1f[(ct * 4 + 1) * 64 + l64], acc, 0, 0, 0);
      acc = __builtin_amdgcn_mfma_f32_16x16x32_f16(a2, W1f[(ct * 4 + 2) * 64 + l64], acc, 0, 0, 0);
      acc = __builtin_amdgcn_mfma_f32_16x16x32_f16(a3, W1f[(ct * 4 + 3) * 64 + l64], acc, 0, 0, 0);
#pragma unroll
      for (int reg = 0; reg < 4; reg++) {
        int row = wv * 16 + lhi * 4 + reg;
        Ul[row * 128 + (col ^ ((row & 7) << 3))] = fmaxf(acc[reg], 0.f);
      }
    }
  }
  __syncthreads();
  // ---- phase 2: V = U @ Wp2 + bp2 ; run-merged atomic seg-max
  {
    f16x8 a[4];
    int arow = wv * 16 + llo;
#pragma unroll
    for (int kt = 0; kt < 4; kt++) {
      int k0 = kt * 32 + lhi * 8;
      const float* src = &Ul[arow * 128 + (k0 ^ ((arow & 7) << 3))];
      float4 s0 = *(const float4*)(src);
      float4 s1 = *(const float4*)(src + 4);
      f16x8 h;
      h[0] = (_Float16)s0.x; h[1] = (_Float16)s0.y;
      h[2] = (_Float16)s0.z; h[3] = (_Float16)s0.w;
      h[4] = (_Float16)s1.x; h[5] = (_Float16)s1.y;
      h[6] = (_Float16)s1.z; h[7] = (_Float16)s1.w;
      a[kt] = h;
    }
#pragma unroll
    for (int ct = 0; ct < 8; ct++) {
      int col = ct * 16 + llo;
      float b2 = b2s[col];
      f32x4 acc = {b2, b2, b2, b2};
      acc = __builtin_amdgcn_mfma_f32_16x16x32_f16(a[0], W2f[(ct * 4 + 0) * 64 + l64], acc, 0, 0, 0);
      acc = __builtin_amdgcn_mfma_f32_16x16x32_f16(a[1], W2f[(ct * 4 + 1) * 64 + l64], acc, 0, 0, 0);
      acc = __builtin_amdgcn_mfma_f32_16x16x32_f16(a[2], W2f[(ct * 4 + 2) * 64 + l64], acc, 0, 0, 0);
      acc = __builtin_amdgcn_mfma_f32_16x16x32_f16(a[3], W2f[(ct * 4 + 3) * 64 + l64], acc, 0, 0, 0);
      int prev_r = -1; float run = 0.f;
#pragma unroll
      for (int reg = 0; reg < 4; reg++) {
        int prow = wv * 16 + lhi * 4 + reg;
        int slot = s_slot[prow];
        if (slot < 0) continue;
        int rr = slot >> 7;
        float v = acc[reg];
        if (rr == prev_r) {
          run = fmaxf(run, v);
        } else {
          if (prev_r >= 0) atomicMax(&msgs_u[prev_r * 128 + col], fkey(run));
          prev_r = rr; run = v;
        }
      }
      if (prev_r >= 0) atomicMax(&msgs_u[prev_r * 128 + col], fkey(run));
    }
  }
}

// ---------------- h = relu(z@Wo1 + msgs@Wo2 + b); LayerNorm -> hidden
__global__ __launch_bounds__(256) void k_out_ln(const float* __restrict__ nf,
    float* __restrict__ hid, const unsigned* __restrict__ msgs_u,
    const float* __restrict__ Wo1, const float* __restrict__ bo1,
    const float* __restrict__ Wo2, const float* __restrict__ bo2,
    const float* __restrict__ ln_s, const float* __restrict__ ln_b, int l) {
  __shared__ float zb[8][256];
  __shared__ float mb[8][128];
  __shared__ float hb[8][128];
  __shared__ float mu[8], rs[8];
  int v0 = blockIdx.x * 8, tid = threadIdx.x;
  for (int idx = tid; idx < 2048; idx += 256) {
    int n = idx >> 8, cc = idx & 255;
    zb[n][cc] = (cc < 128) ? nf[(v0 + n) * 128 + cc]
                           : hid[(v0 + n) * 128 + (cc - 128)];
  }
  for (int idx = tid; idx < 1024; idx += 256) {
    int n = idx >> 7, cc = idx & 127;
    mb[n][cc] = funkey(msgs_u[(v0 + n) * 128 + cc]);
  }
  __syncthreads();
  int c = tid & 127, ng = tid >> 7;
  float binit = bo1[l * 128 + c] + bo2[l * 128 + c];
  float acc[4];
#pragma unroll
  for (int q = 0; q < 4; q++) acc[q] = binit;
  const float* W1 = Wo1 + l * 32768;
  for (int k = 0; k < 256; k += 4) {
    float w0 = W1[k * 128 + c], w1 = W1[(k + 1) * 128 + c];
    float w2 = W1[(k + 2) * 128 + c], w3 = W1[(k + 3) * 128 + c];
#pragma unroll
    for (int q = 0; q < 4; q++) {
      float4 z4 = *(const float4*)&zb[ng * 4 + q][k];
      acc[q] += z4.x * w0 + z4.y * w1 + z4.z * w2 + z4.w * w3;
    }
  }
  const float* W2 = Wo2 + l * 16384;
  for (int k = 0; k < 128; k += 4) {
    float w0 = W2[k * 128 + c], w1 = W2[(k + 1) * 128 + c];
    float w2 = W2[(k + 2) * 128 + c], w3 = W2[(k + 3) * 128 + c];
#pragma unroll
    for (int q = 0; q < 4; q++) {
      float4 m4 = *(const float4*)&mb[ng * 4 + q][k];
      acc[q] += m4.x * w0 + m4.y * w1 + m4.z * w2 + m4.w * w3;
    }
  }
#pragma unroll
  for (int q = 0; q < 4; q++) hb[ng * 4 + q][c] = fmaxf(acc[q], 0.f);
  __syncthreads();
  {
    int n = tid >> 5, l32 = tid & 31;
    float s = hb[n][l32] + hb[n][l32 + 32] + hb[n][l32 + 64] + hb[n][l32 + 96];
#pragma unroll
    for (int m = 16; m >= 1; m >>= 1) s += __shfl_xor(s, m, 64);
    if (l32 == 0) mu[n] = s * (1.f / 128.f);
  }
  __syncthreads();
  {
    int n = tid >> 5, l32 = tid & 31;
    float m = mu[n];
    float d0 = hb[n][l32] - m, d1 = hb[n][l32 + 32] - m;
    float d2 = hb[n][l32 + 64] - m, d3 = hb[n][l32 + 96] - m;
    float s = d0 * d0 + d1 * d1 + d2 * d2 + d3 * d3;
#pragma unroll
    for (int m2 = 16; m2 >= 1; m2 >>= 1) s += __shfl_xor(s, m2, 64);
    if (l32 == 0) rs[n] = rsqrtf(s * (1.f / 128.f) + 1e-5f);
  }
  __syncthreads();
  float sc = ln_s[l * 128 + c], bb = ln_b[l * 128 + c];
#pragma unroll
  for (int q = 0; q < 4; q++) {
    int n = ng * 4 + q;
    hid[(v0 + n) * 128 + c] = (hb[n][c] - mu[n]) * rs[n] * sc + bb;
  }
}

// ---------------- mean pool over nodes + 2-layer head
__global__ __launch_bounds__(128) void k_head(const float* __restrict__ hid,
    const float* __restrict__ Wh1, const float* __restrict__ bh1,
    const float* __restrict__ Wh2, const float* __restrict__ bh2,
    float* __restrict__ out) {
  __shared__ float ge[128], p1[128];
  int b = blockIdx.x, t = threadIdx.x;
  float s = 0.f;
  for (int n = 0; n < 128; n++) s += hid[(b * 128 + n) * 128 + t];
  ge[t] = s * (1.f / 128.f);
  __syncthreads();
  float a = bh1[t];
  for (int k = 0; k < 128; k++) a += ge[k] * Wh1[k * 128 + t];
  p1[t] = fmaxf(a, 0.f);
  __syncthreads();
  float o = bh2[t];
  for (int k = 0; k < 128; k++) o += p1[k] * Wh2[k * 128 + t];
  out[b * 128 + t] = o;
}

extern "C" void kernel_launch(void* const* d_in, const int* in_sizes, int n_in,
                              void* d_out, int out_size, void* d_ws, size_t ws_size,
                              hipStream_t stream) {
  const int* x          = (const int*)d_in[0];
  const int* edge_attr  = (const int*)d_in[1];
  const int* edge_index = (const int*)d_in[2];
  const float* atom_emb = (const float*)d_in[4];
  const float* bond_emb = (const float*)d_in[5];
  const float* Wm1 = (const float*)d_in[6];
  const float* bm1 = (const float*)d_in[7];
  const float* Wm2 = (const float*)d_in[8];
  const float* bm2 = (const float*)d_in[9];
  const float* We  = (const float*)d_in[10];
  const float* be  = (const float*)d_in[11];
  const float* bg  = (const float*)d_in[13];   // Wg dead: graph_fts == 0
  const float* Wp1 = (const float*)d_in[14];
  const float* bp1 = (const float*)d_in[15];
  const float* Wp2 = (const float*)d_in[16];
  const float* bp2 = (const float*)d_in[17];
  const float* Wo1 = (const float*)d_in[18];
  const float* bo1 = (const float*)d_in[19];
  const float* Wo2 = (const float*)d_in[20];
  const float* bo2 = (const float*)d_in[21];
  const float* ln_s = (const float*)d_in[22];
  const float* ln_b = (const float*)d_in[23];
  const float* Wh1 = (const float*)d_in[24];
  const float* bh1 = (const float*)d_in[25];
  const float* Wh2 = (const float*)d_in[26];
  const float* bh2 = (const float*)d_in[27];
  float* out = (float*)d_out;

  // workspace carve-up (~20 MB)
  int* cnt       = (int*)d_ws;                  // 524288
  int* basep     = cnt + SLOTS_;                // 524288
  int* cursor    = basep + SLOTS_;              // 524288
  int* pairbase  = cursor + SLOTS_;             // 524288
  int* bsumA     = pairbase + SLOTS_;           // 2048
  int* bsumF     = bsumA + 2048;                // 2048
  int* pair_tot  = bsumF + 2048;                // 16
  int* sorted_e  = pair_tot + 16;               // 65536
  int* pair_slot = sorted_e + EE_;              // 65536
  int* pair_off  = pair_slot + EE_;             // 65536
  int* pair_cnt  = pair_off + EE_;              // 65536
  float* node_fts = (float*)(pair_cnt + EE_);   // 524288 f
  float* hidden   = node_fts + SLOTS_;          // 524288 f
  float* m1       = hidden + SLOTS_;            // 524288 f
  float* m2       = m1 + SLOTS_;                // 524288 f
  unsigned* msgs_u = (unsigned*)(m2 + SLOTS_);  // 524288 u
  float* bembWe   = (float*)(msgs_u + SLOTS_);  // 6144 f
  _Float16* Whf   = (_Float16*)(bembWe + 6144); // 98304 h

  hipMemsetAsync(cnt, 0, SLOTS_ * sizeof(int), stream);
  hipMemsetAsync(hidden, 0, SLOTS_ * sizeof(float), stream);

  k_node_enc<<<NODES_, 128, 0, stream>>>(x, atom_emb, node_fts);
  k_wprep<<<48, 256, 0, stream>>>(Wp1, Wp2, Whf);
  k_edge_count<<<EE_ / 256, 256, 0, stream>>>(edge_index, cnt);
  k_scanA<<<SLOTS_ / 256, 256, 0, stream>>>(cnt, basep, pairbase, bsumA, bsumF);
  k_scan2d<<<2, 256, 0, stream>>>(bsumA, bsumF);
  k_scanB<<<SLOTS_ / 256, 256, 0, stream>>>(cnt, basep, pairbase, cursor, bsumA,
                                            bsumF, pair_tot, pair_slot,
                                            pair_off, pair_cnt);
  k_edge_scatter<<<EE_ / 256, 256, 0, stream>>>(edge_index, cursor, sorted_e);

  for (int l = 0; l < LL_; l++) {
    k_m12<<<NODES_ / 8, 256, 0, stream>>>(node_fts, hidden, Wm1, bm1, Wm2, bm2,
                                          m1, m2, msgs_u, l);
    k_bembWe<<<48, 128, 0, stream>>>(bond_emb, We, bembWe, l);
    k_pairs<<<1024, 256, 0, stream>>>(m1, m2, pair_slot, pair_off, pair_cnt,
                                      pair_tot, sorted_e, edge_attr, bembWe,
                                      be, bg, Whf, bp1, bp2, msgs_u, l);
    k_out_ln<<<NODES_ / 8, 256, 0, stream>>>(node_fts, hidden, msgs_u, Wo1, bo1,
                                             Wo2, bo2, ln_s, ln_b, l);
  }
  k_head<<<NB_, 128, 0, stream>>>(hidden, Wh1, bh1, Wh2, bh2, out);
}

// Round 5
// 382.986 us; speedup vs baseline: 6.6106x; 1.1539x over previous
//
#include <hip/hip_runtime.h>
#include <hip/hip_bf16.h>

#define NB_ 32
#define LL_ 3
#define EE_ 65536
#define NODES_ 4096
#define SLOTS_ 524288   // NODES_ * 128
#define NEGV -1e9f

typedef _Float16 f16x8 __attribute__((ext_vector_type(8)));
typedef float f32x4 __attribute__((ext_vector_type(4)));

// order-preserving float->uint key (max over keys == max over floats)
__device__ __forceinline__ unsigned fkey(float f) {
  unsigned b = __float_as_uint(f);
  unsigned m = ((int)b >> 31) | 0x80000000u;
  return b ^ m;
}
__device__ __forceinline__ float funkey(unsigned k) {
  unsigned xm = (k & 0x80000000u) ? 0x80000000u : 0xFFFFFFFFu;
  return __uint_as_float(k ^ xm);
}

// ---------------- node encoder -> zh f16 [4096][256] (cols 0-127 nf, 128-255 hidden=0)
__global__ __launch_bounds__(128) void k_node_enc(const int* __restrict__ x,
    const float* __restrict__ atom_emb, _Float16* __restrict__ zh) {
  int v = blockIdx.x, t = threadIdx.x;
  float acc = 0.f;
#pragma unroll
  for (int c = 0; c < 9; c++) {
    int xv = x[v * 9 + c];
    acc += atom_emb[(c * 128 + xv) * 128 + t];
  }
  zh[v * 256 + t] = (_Float16)acc;
  zh[v * 256 + 128 + t] = (_Float16)0.f;
}

// ---------------- edge histogram into receiver-major pair slots
__global__ __launch_bounds__(256) void k_edge_count(const int* __restrict__ ei,
                                                    int* __restrict__ cnt) {
  int e = blockIdx.x * 256 + threadIdx.x;
  int s = ei[e], d = ei[EE_ + e];
  int g = s >> 7, i = s & 127, j = d & 127;
  int slot = ((g << 7) + j) * 128 + i;   // receiver-major
  atomicAdd(&cnt[slot], 1);
}

// ---------------- fused block-scan: edge-count scan + pair-flag scan
__global__ __launch_bounds__(256) void k_scanA(const int* __restrict__ cnt,
    int* __restrict__ base, int* __restrict__ pairbase,
    int* __restrict__ bsumA, int* __restrict__ bsumF) {
  __shared__ int sA[256], sF[256];
  int t = threadIdx.x, gid = blockIdx.x * 256 + t;
  int v = cnt[gid];
  int f = v > 0 ? 1 : 0;
  sA[t] = v; sF[t] = f; __syncthreads();
  for (int st = 1; st < 256; st <<= 1) {
    int aA = sA[t], aF = sF[t];
    int bA = (t >= st) ? sA[t - st] : 0;
    int bF = (t >= st) ? sF[t - st] : 0;
    __syncthreads();
    sA[t] = aA + bA; sF[t] = aF + bF;
    __syncthreads();
  }
  base[gid] = sA[t] - v;
  pairbase[gid] = sF[t] - f;
  if (t == 255) { bsumA[blockIdx.x] = sA[255]; bsumF[blockIdx.x] = sF[255]; }
}

// ---------------- scan of the 2048 block sums (block 0: A, block 1: F)
__global__ __launch_bounds__(256) void k_scan2d(int* __restrict__ bsumA,
                                                int* __restrict__ bsumF) {
  int* bsum = blockIdx.x ? bsumF : bsumA;
  __shared__ int s[256];
  int t = threadIdx.x;
  int v[8]; int tot = 0;
#pragma unroll
  for (int q = 0; q < 8; q++) { v[q] = bsum[t * 8 + q]; tot += v[q]; }
  s[t] = tot; __syncthreads();
  for (int st = 1; st < 256; st <<= 1) {
    int a = s[t]; int b = (t >= st) ? s[t - st] : 0;
    __syncthreads(); s[t] = a + b; __syncthreads();
  }
  int run = s[t] - tot;
#pragma unroll
  for (int q = 0; q < 8; q++) { int tmp = v[q]; bsum[t * 8 + q] = run; run += tmp; }
}

// ---------------- finalize scans + build compact pair arrays
__global__ __launch_bounds__(256) void k_scanB(const int* __restrict__ cnt,
    int* __restrict__ base, const int* __restrict__ pairbase,
    int* __restrict__ cursor, const int* __restrict__ bsumA,
    const int* __restrict__ bsumF, int* __restrict__ pair_total,
    int* __restrict__ pair_slot, int* __restrict__ pair_off,
    int* __restrict__ pair_cnt) {
  int gid = blockIdx.x * 256 + threadIdx.x;
  int b = base[gid] + bsumA[gid >> 8];
  int pb = pairbase[gid] + bsumF[gid >> 8];
  base[gid] = b; cursor[gid] = b;
  int c = cnt[gid];
  if (c > 0) {
    pair_slot[pb] = gid;
    pair_off[pb] = b;
    pair_cnt[pb] = c;
  }
  if (gid == SLOTS_ - 1) pair_total[0] = pb + (c > 0 ? 1 : 0);
}

// ---------------- scatter edge ids into receiver-major sorted order
__global__ __launch_bounds__(256) void k_edge_scatter(const int* __restrict__ ei,
    int* __restrict__ cursor, int* __restrict__ sorted_e) {
  int e = blockIdx.x * 256 + threadIdx.x;
  int s = ei[e], d = ei[EE_ + e];
  int g = s >> 7, i = s & 127, j = d & 127;
  int slot = ((g << 7) + j) * 128 + i;
  int pos = atomicAdd(&cursor[slot], 1);
  sorted_e[pos] = e;
}

// ---------------- weight prep: all MFMA weights -> fp16 fragment-major
// B-frag convention: lane l holds col = ct*16 + (l&15), k = kt*32 + (l>>4)*8 + e
// layout (f16x8 units):
//   [0,12288):      Wp1/Wp2, mat=lyr*2+which, frag (ct*4+kt)*64+lane
//   [12288,36864):  Wm12 (cols 0-127=Wm1, 128-255=Wm2), per layer 8192, frag (ct*8+kt)*64+lane
//   [36864,55296):  Wo12 (k 0-255=Wo1, 256-383=Wo2), per layer 6144, frag (ct*12+kt)*64+lane
__global__ __launch_bounds__(256) void k_wprep(const float* __restrict__ Wp1,
    const float* __restrict__ Wp2, const float* __restrict__ Wm1,
    const float* __restrict__ Wm2, const float* __restrict__ Wo1,
    const float* __restrict__ Wo2, _Float16* __restrict__ Whf) {
  int gid = blockIdx.x * 256 + threadIdx.x;   // 0..55295
  int lane = gid & 63;
  int llo = lane & 15, lhi = lane >> 4;
  const float* W; int col, kbase;
  if (gid < 12288) {
    int mat = gid >> 11, pos = gid & 2047;
    int fr = pos >> 6; int ct = fr >> 2, kt = fr & 3;
    int lyr = mat >> 1, which = mat & 1;
    W = (which ? Wp2 : Wp1) + lyr * 16384;
    col = ct * 16 + llo; kbase = kt * 32 + lhi * 8;
  } else if (gid < 36864) {
    int q = gid - 12288;
    int lyr = q >> 13, r = q & 8191;
    int fr = r >> 6; int ct = fr >> 3, kt = fr & 7;
    col = ct * 16 + llo; kbase = kt * 32 + lhi * 8;
    if (col < 128) { W = Wm1 + lyr * 32768; }
    else { W = Wm2 + lyr * 32768; col -= 128; }
  } else {
    int q = gid - 36864;
    int lyr = q / 6144, r = q % 6144;
    int fr = r >> 6; int ct = fr / 12, kt = fr % 12;
    col = ct * 16 + llo; kbase = kt * 32 + lhi * 8;
    if (kbase < 256) { W = Wo1 + lyr * 32768; }
    else { W = Wo2 + lyr * 16384; kbase -= 256; }
  }
  f16x8 h;
#pragma unroll
  for (int e = 0; e < 8; e++) h[e] = (_Float16)W[(kbase + e) * 128 + col];
  ((f16x8*)Whf)[gid] = h;
}

// ---------------- bembWeh[l] = f16(bond_emb @ We[l]) for all 3 layers
__global__ __launch_bounds__(128) void k_bembWe(const float* __restrict__ bond_emb,
    const float* __restrict__ We, _Float16* __restrict__ bembWeh) {
  __shared__ float row[128];
  int id = blockIdx.x;               // 0..143
  int l = id / 48, rr = id % 48;
  int c = threadIdx.x;
  row[c] = bond_emb[rr * 128 + c];
  __syncthreads();
  const float* W = We + l * 16384;
  float acc = 0.f;
  for (int k = 0; k < 128; k += 4) {
    acc += row[k] * W[k * 128 + c] + row[k + 1] * W[(k + 1) * 128 + c] +
           row[k + 2] * W[(k + 2) * 128 + c] + row[k + 3] * W[(k + 3) * 128 + c];
  }
  bembWeh[(l * 48 + rr) * 128 + c] = (_Float16)acc;
}

// ---------------- m12 MFMA: mm[4096,256] = zh @ [Wm1||Wm2] + b ; fused msgs init
__global__ __launch_bounds__(64) void k_m12(const _Float16* __restrict__ zh,
    const _Float16* __restrict__ Whf, const float* __restrict__ bm1,
    const float* __restrict__ bm2, _Float16* __restrict__ mm,
    unsigned* __restrict__ msgs_u, int l) {
  int tid = threadIdx.x;
  {  // msgs re-init: 256 blocks * 64 thr * 32 = 524288
    int g0 = blockIdx.x * 64 + tid;
    unsigned kneg = fkey(NEGV);
#pragma unroll
    for (int q = 0; q < 32; q++) msgs_u[g0 + q * 16384] = kneg;
  }
  int llo = tid & 15, lhi = tid >> 4;
  int row = blockIdx.x * 16 + llo;
  f16x8 a[8];
#pragma unroll
  for (int kt = 0; kt < 8; kt++)
    a[kt] = *(const f16x8*)(zh + row * 256 + kt * 32 + lhi * 8);
  const f16x8* Bf = (const f16x8*)Whf + 12288 + l * 8192;
#pragma unroll
  for (int ct = 0; ct < 16; ct++) {
    int col = ct * 16 + llo;
    float bv = (col < 128) ? bm1[l * 128 + col] : bm2[l * 128 + col - 128];
    f32x4 acc = {bv, bv, bv, bv};
#pragma unroll
    for (int kt = 0; kt < 8; kt++)
      acc = __builtin_amdgcn_mfma_f32_16x16x32_f16(a[kt], Bf[(ct * 8 + kt) * 64 + tid], acc, 0, 0, 0);
#pragma unroll
    for (int reg = 0; reg < 4; reg++)
      mm[(blockIdx.x * 16 + lhi * 4 + reg) * 256 + col] = (_Float16)acc[reg];
  }
}

// ---------------- MFMA pair MLP: 64 pairs/block, reg A-frags, f16 U in LDS
__global__ __launch_bounds__(256, 4) void k_pairs(
    const _Float16* __restrict__ mm,
    const int* __restrict__ pair_slot, const int* __restrict__ pair_off,
    const int* __restrict__ pair_cnt, const int* __restrict__ pair_total,
    const int* __restrict__ sorted_e, const int* __restrict__ edge_attr,
    const _Float16* __restrict__ bembWeh,
    const float* __restrict__ be, const float* __restrict__ bg,
    const _Float16* __restrict__ Whf,
    const float* __restrict__ bp1, const float* __restrict__ bp2,
    unsigned* __restrict__ msgs_u, int l) {
  __shared__ int s_slot[64], s_off[64], s_cnt[64];
  __shared__ _Float16 Uh[64 * 128];   // granule-XOR swizzled, 16 KB
  int P = pair_total[0];
  int pid0 = blockIdx.x * 64;
  if (pid0 >= P) return;
  int tid = threadIdx.x;
  if (tid < 64) {
    int pid = pid0 + tid;
    bool va = pid < P;
    s_slot[tid] = va ? pair_slot[pid] : -1;
    s_off[tid] = va ? pair_off[pid] : 0;
    s_cnt[tid] = va ? pair_cnt[pid] : 0;
  }
  __syncthreads();
  int l64 = tid & 63, wv = tid >> 6;
  int llo = l64 & 15, lhi = l64 >> 4;
  int p = wv * 16 + llo;
  int slot = s_slot[p];
  float t32[4][8];
  if (slot >= 0) {
    int rr = slot >> 7, i = slot & 127, g = slot >> 14;
    int sn = (g << 7) + i;
#pragma unroll
    for (int kt = 0; kt < 4; kt++) {
      int c0 = kt * 32 + lhi * 8;
      f16x8 v1 = *(const f16x8*)(mm + sn * 256 + c0);         // m1[sender]
      f16x8 v2 = *(const f16x8*)(mm + rr * 256 + 128 + c0);   // m2[receiver]
      float4 e0 = *(const float4*)(be + l * 128 + c0);
      float4 e1 = *(const float4*)(be + l * 128 + c0 + 4);
      float4 g0 = *(const float4*)(bg + l * 128 + c0);
      float4 g1 = *(const float4*)(bg + l * 128 + c0 + 4);
      t32[kt][0] = (float)v1[0] + (float)v2[0] + e0.x + g0.x;
      t32[kt][1] = (float)v1[1] + (float)v2[1] + e0.y + g0.y;
      t32[kt][2] = (float)v1[2] + (float)v2[2] + e0.z + g0.z;
      t32[kt][3] = (float)v1[3] + (float)v2[3] + e0.w + g0.w;
      t32[kt][4] = (float)v1[4] + (float)v2[4] + e1.x + g1.x;
      t32[kt][5] = (float)v1[5] + (float)v2[5] + e1.y + g1.y;
      t32[kt][6] = (float)v1[6] + (float)v2[6] + e1.z + g1.z;
      t32[kt][7] = (float)v1[7] + (float)v2[7] + e1.w + g1.w;
    }
    int off = s_off[p], cn = s_cnt[p];
    for (int d = 0; d < cn; d++) {
      int eid = sorted_e[off + d];
      int a0 = edge_attr[eid * 3], a1 = edge_attr[eid * 3 + 1],
          a2 = edge_attr[eid * 3 + 2];
      const _Float16* r0 = bembWeh + (l * 48 + a0) * 128;
      const _Float16* r1 = bembWeh + (l * 48 + 16 + a1) * 128;
      const _Float16* r2 = bembWeh + (l * 48 + 32 + a2) * 128;
#pragma unroll
      for (int kt = 0; kt < 4; kt++) {
        int c0 = kt * 32 + lhi * 8;
        f16x8 x0 = *(const f16x8*)(r0 + c0);
        f16x8 x1 = *(const f16x8*)(r1 + c0);
        f16x8 x2 = *(const f16x8*)(r2 + c0);
#pragma unroll
        for (int e = 0; e < 8; e++)
          t32[kt][e] += (float)x0[e] + (float)x1[e] + (float)x2[e];
      }
    }
  } else {
#pragma unroll
    for (int kt = 0; kt < 4; kt++)
#pragma unroll
      for (int e = 0; e < 8; e++) t32[kt][e] = 0.f;
  }
  f16x8 a[4];
#pragma unroll
  for (int kt = 0; kt < 4; kt++)
#pragma unroll
    for (int e = 0; e < 8; e++) a[kt][e] = (_Float16)fmaxf(t32[kt][e], 0.f);

  const f16x8* W1f = (const f16x8*)Whf + (l * 2) * 2048;
  const f16x8* W2f = (const f16x8*)Whf + (l * 2 + 1) * 2048;
  // ---- phase 1: U = relu(T @ Wp1 + bp1) -> swizzled f16 LDS
#pragma unroll
  for (int ct = 0; ct < 8; ct++) {
    int col = ct * 16 + llo;
    float b1 = bp1[l * 128 + col];
    f32x4 acc = {b1, b1, b1, b1};
#pragma unroll
    for (int kt = 0; kt < 4; kt++)
      acc = __builtin_amdgcn_mfma_f32_16x16x32_f16(a[kt], W1f[(ct * 4 + kt) * 64 + l64], acc, 0, 0, 0);
#pragma unroll
    for (int reg = 0; reg < 4; reg++) {
      int wrow = wv * 16 + lhi * 4 + reg;
      int sg = (2 * ct + (llo >> 3)) ^ (wrow & 15);
      Uh[wrow * 128 + sg * 8 + (llo & 7)] = (_Float16)fmaxf(acc[reg], 0.f);
    }
  }
  __syncthreads();
  // ---- phase 2: V = U @ Wp2 + bp2 ; run-merged atomic seg-max
  f16x8 a2[4];
  int arow = wv * 16 + llo;
#pragma unroll
  for (int kt = 0; kt < 4; kt++) {
    int sg = (kt * 4 + lhi) ^ (arow & 15);
    a2[kt] = *(const f16x8*)(Uh + arow * 128 + sg * 8);
  }
#pragma unroll
  for (int ct = 0; ct < 8; ct++) {
    int col = ct * 16 + llo;
    float b2 = bp2[l * 128 + col];
    f32x4 acc = {b2, b2, b2, b2};
#pragma unroll
    for (int kt = 0; kt < 4; kt++)
      acc = __builtin_amdgcn_mfma_f32_16x16x32_f16(a2[kt], W2f[(ct * 4 + kt) * 64 + l64], acc, 0, 0, 0);
    int prev_r = -1; float run = 0.f;
#pragma unroll
    for (int reg = 0; reg < 4; reg++) {
      int prow = wv * 16 + lhi * 4 + reg;
      int slot2 = s_slot[prow];
      if (slot2 < 0) continue;
      int rr = slot2 >> 7;
      float v = acc[reg];
      if (rr == prev_r) {
        run = fmaxf(run, v);
      } else {
        if (prev_r >= 0) atomicMax(&msgs_u[prev_r * 128 + col], fkey(run));
        prev_r = rr; run = v;
      }
    }
    if (prev_r >= 0) atomicMax(&msgs_u[prev_r * 128 + col], fkey(run));
  }
}

// ---------------- out+LN MFMA: h=relu([zh||msgs]@[Wo1;Wo2]+b); LN -> zh hid half
__global__ __launch_bounds__(64) void k_out_ln(_Float16* __restrict__ zh,
    const unsigned* __restrict__ msgs_u, const _Float16* __restrict__ Whf,
    const float* __restrict__ bo1, const float* __restrict__ bo2,
    const float* __restrict__ ln_s, const float* __restrict__ ln_b, int l) {
  int tid = threadIdx.x;
  int llo = tid & 15, lhi = tid >> 4;
  int row = blockIdx.x * 16 + llo;
  f16x8 a[12];
#pragma unroll
  for (int kt = 0; kt < 8; kt++)
    a[kt] = *(const f16x8*)(zh + row * 256 + kt * 32 + lhi * 8);
#pragma unroll
  for (int kt = 8; kt < 12; kt++) {
    int k0 = (kt - 8) * 32 + lhi * 8;
    f16x8 h;
#pragma unroll
    for (int e = 0; e < 8; e++) {
      float v = funkey(msgs_u[row * 128 + k0 + e]);
      v = fmaxf(fminf(v, 60000.f), -60000.f);   // f16-safe (isolated-recv NEG)
      h[e] = (_Float16)v;
    }
    a[kt] = h;
  }
  const f16x8* Bf = (const f16x8*)Whf + 36864 + l * 6144;
  float h[8][4];
#pragma unroll
  for (int ct = 0; ct < 8; ct++) {
    int col = ct * 16 + llo;
    float bv = bo1[l * 128 + col] + bo2[l * 128 + col];
    f32x4 acc = {bv, bv, bv, bv};
#pragma unroll
    for (int kt = 0; kt < 12; kt++)
      acc = __builtin_amdgcn_mfma_f32_16x16x32_f16(a[kt], Bf[(ct * 12 + kt) * 64 + tid], acc, 0, 0, 0);
#pragma unroll
    for (int reg = 0; reg < 4; reg++) h[ct][reg] = fmaxf(acc[reg], 0.f);
  }
  float mu[4], rs[4];
#pragma unroll
  for (int reg = 0; reg < 4; reg++) {
    float s = 0.f;
#pragma unroll
    for (int ct = 0; ct < 8; ct++) s += h[ct][reg];
    s += __shfl_xor(s, 1, 64); s += __shfl_xor(s, 2, 64);
    s += __shfl_xor(s, 4, 64); s += __shfl_xor(s, 8, 64);
    mu[reg] = s * (1.f / 128.f);
  }
#pragma unroll
  for (int reg = 0; reg < 4; reg++) {
    float s = 0.f;
#pragma unroll
    for (int ct = 0; ct < 8; ct++) { float d = h[ct][reg] - mu[reg]; s += d * d; }
    s += __shfl_xor(s, 1, 64); s += __shfl_xor(s, 2, 64);
    s += __shfl_xor(s, 4, 64); s += __shfl_xor(s, 8, 64);
    rs[reg] = rsqrtf(s * (1.f / 128.f) + 1e-5f);
  }
#pragma unroll
  for (int ct = 0; ct < 8; ct++) {
    int col = ct * 16 + llo;
    float sc = ln_s[l * 128 + col], bb = ln_b[l * 128 + col];
#pragma unroll
    for (int reg = 0; reg < 4; reg++) {
      int wrow = blockIdx.x * 16 + lhi * 4 + reg;
      zh[wrow * 256 + 128 + col] =
          (_Float16)((h[ct][reg] - mu[reg]) * rs[reg] * sc + bb);
    }
  }
}

// ---------------- mean pool over nodes + 2-layer head (fp32)
__global__ __launch_bounds__(128) void k_head(const _Float16* __restrict__ zh,
    const float* __restrict__ Wh1, const float* __restrict__ bh1,
    const float* __restrict__ Wh2, const float* __restrict__ bh2,
    float* __restrict__ out) {
  __shared__ float ge[128], p1[128];
  int b = blockIdx.x, t = threadIdx.x;
  float s = 0.f;
  for (int n = 0; n < 128; n++) s += (float)zh[(b * 128 + n) * 256 + 128 + t];
  ge[t] = s * (1.f / 128.f);
  __syncthreads();
  float a = bh1[t];
  for (int k = 0; k < 128; k++) a += ge[k] * Wh1[k * 128 + t];
  p1[t] = fmaxf(a, 0.f);
  __syncthreads();
  float o = bh2[t];
  for (int k = 0; k < 128; k++) o += p1[k] * Wh2[k * 128 + t];
  out[b * 128 + t] = o;
}

extern "C" void kernel_launch(void* const* d_in, const int* in_sizes, int n_in,
                              void* d_out, int out_size, void* d_ws, size_t ws_size,
                              hipStream_t stream) {
  const int* x          = (const int*)d_in[0];
  const int* edge_attr  = (const int*)d_in[1];
  const int* edge_index = (const int*)d_in[2];
  const float* atom_emb = (const float*)d_in[4];
  const float* bond_emb = (const float*)d_in[5];
  const float* Wm1 = (const float*)d_in[6];
  const float* bm1 = (const float*)d_in[7];
  const float* Wm2 = (const float*)d_in[8];
  const float* bm2 = (const float*)d_in[9];
  const float* We  = (const float*)d_in[10];
  const float* be  = (const float*)d_in[11];
  const float* bg  = (const float*)d_in[13];   // Wg dead: graph_fts == 0
  const float* Wp1 = (const float*)d_in[14];
  const float* bp1 = (const float*)d_in[15];
  const float* Wp2 = (const float*)d_in[16];
  const float* bp2 = (const float*)d_in[17];
  const float* Wo1 = (const float*)d_in[18];
  const float* bo1 = (const float*)d_in[19];
  const float* Wo2 = (const float*)d_in[20];
  const float* bo2 = (const float*)d_in[21];
  const float* ln_s = (const float*)d_in[22];
  const float* ln_b = (const float*)d_in[23];
  const float* Wh1 = (const float*)d_in[24];
  const float* bh1 = (const float*)d_in[25];
  const float* Wh2 = (const float*)d_in[26];
  const float* bh2 = (const float*)d_in[27];
  float* out = (float*)d_out;

  // workspace carve-up (~16 MB)
  int* cnt       = (int*)d_ws;                  // 524288
  int* basep     = cnt + SLOTS_;                // 524288
  int* cursor    = basep + SLOTS_;              // 524288
  int* pairbase  = cursor + SLOTS_;             // 524288
  int* bsumA     = pairbase + SLOTS_;           // 2048
  int* bsumF     = bsumA + 2048;                // 2048
  int* pair_tot  = bsumF + 2048;                // 16
  int* sorted_e  = pair_tot + 16;               // 65536
  int* pair_slot = sorted_e + EE_;              // 65536
  int* pair_off  = pair_slot + EE_;             // 65536
  int* pair_cnt  = pair_off + EE_;              // 65536
  unsigned* msgs_u = (unsigned*)(pair_cnt + EE_);   // 524288 u32
  _Float16* zh   = (_Float16*)(msgs_u + SLOTS_);    // 4096*256 f16
  _Float16* mm   = zh + NODES_ * 256;               // 4096*256 f16
  _Float16* bembWeh = mm + NODES_ * 256;            // 3*48*128 f16
  _Float16* Whf  = bembWeh + 3 * 48 * 128;          // 55296*8 f16

  hipMemsetAsync(cnt, 0, SLOTS_ * sizeof(int), stream);

  k_node_enc<<<NODES_, 128, 0, stream>>>(x, atom_emb, zh);
  k_wprep<<<216, 256, 0, stream>>>(Wp1, Wp2, Wm1, Wm2, Wo1, Wo2, Whf);
  k_bembWe<<<144, 128, 0, stream>>>(bond_emb, We, bembWeh);
  k_edge_count<<<EE_ / 256, 256, 0, stream>>>(edge_index, cnt);
  k_scanA<<<SLOTS_ / 256, 256, 0, stream>>>(cnt, basep, pairbase, bsumA, bsumF);
  k_scan2d<<<2, 256, 0, stream>>>(bsumA, bsumF);
  k_scanB<<<SLOTS_ / 256, 256, 0, stream>>>(cnt, basep, pairbase, cursor, bsumA,
                                            bsumF, pair_tot, pair_slot,
                                            pair_off, pair_cnt);
  k_edge_scatter<<<EE_ / 256, 256, 0, stream>>>(edge_index, cursor, sorted_e);

  for (int l = 0; l < LL_; l++) {
    k_m12<<<NODES_ / 16, 64, 0, stream>>>(zh, Whf, bm1, bm2, mm, msgs_u, l);
    k_pairs<<<1024, 256, 0, stream>>>(mm, pair_slot, pair_off, pair_cnt,
                                      pair_tot, sorted_e, edge_attr, bembWeh,
                                      be, bg, Whf, bp1, bp2, msgs_u, l);
    k_out_ln<<<NODES_ / 16, 64, 0, stream>>>(zh, msgs_u, Whf, bo1, bo2,
                                             ln_s, ln_b, l);
  }
  k_head<<<NB_, 128, 0, stream>>>(zh, Wh1, bh1, Wh2, bh2, out);
}

// Round 6
// 267.758 us; speedup vs baseline: 9.4554x; 1.4303x over previous
//
#include <hip/hip_runtime.h>
#include <hip/hip_bf16.h>

#define NB_ 32
#define LL_ 3
#define EE_ 65536
#define NODES_ 4096
#define SLOTS_ 524288   // NODES_ * 128
#define NEGV -1e9f

typedef _Float16 f16x8 __attribute__((ext_vector_type(8)));
typedef float f32x4 __attribute__((ext_vector_type(4)));

// order-preserving float->uint key (max over keys == max over floats)
__device__ __forceinline__ unsigned fkey(float f) {
  unsigned b = __float_as_uint(f);
  unsigned m = ((int)b >> 31) | 0x80000000u;
  return b ^ m;
}
__device__ __forceinline__ float funkey(unsigned k) {
  unsigned xm = (k & 0x80000000u) ? 0x80000000u : 0xFFFFFFFFu;
  return __uint_as_float(k ^ xm);
}

// ---------------- fused prologue: node_enc | wprep | bembWe | edge_count+rank
// blocks [0,2048): node encoder (2 nodes/block) -> zh f16 [4096][256]
// blocks [2048,2264): weight prep -> Whf fragment-major fp16
// blocks [2264,2336): bembWeh = f16(bond_emb @ We[l]) for 3 layers (2 rows/blk)
// blocks [2336,2592): edge histogram + per-edge rank
__global__ __launch_bounds__(256) void k_pro(const int* __restrict__ x,
    const float* __restrict__ atom_emb, _Float16* __restrict__ zh,
    const float* __restrict__ Wp1, const float* __restrict__ Wp2,
    const float* __restrict__ Wm1, const float* __restrict__ Wm2,
    const float* __restrict__ Wo1, const float* __restrict__ Wo2,
    _Float16* __restrict__ Whf,
    const float* __restrict__ bond_emb, const float* __restrict__ We,
    _Float16* __restrict__ bembWeh,
    const int* __restrict__ ei, int* __restrict__ cnt, int* __restrict__ erank) {
  int blk = blockIdx.x, tid = threadIdx.x;
  if (blk < 2048) {
    int v = blk * 2 + (tid >> 7), t = tid & 127;
    float acc = 0.f;
#pragma unroll
    for (int c = 0; c < 9; c++) {
      int xv = x[v * 9 + c];
      acc += atom_emb[(c * 128 + xv) * 128 + t];
    }
    zh[v * 256 + t] = (_Float16)acc;
    zh[v * 256 + 128 + t] = (_Float16)0.f;
  } else if (blk < 2264) {
    int gid = (blk - 2048) * 256 + tid;   // 0..55295
    int lane = gid & 63;
    int llo = lane & 15, lhi = lane >> 4;
    const float* W; int col, kbase;
    if (gid < 12288) {
      int mat = gid >> 11, pos = gid & 2047;
      int fr = pos >> 6; int ct = fr >> 2, kt = fr & 3;
      int lyr = mat >> 1, which = mat & 1;
      W = (which ? Wp2 : Wp1) + lyr * 16384;
      col = ct * 16 + llo; kbase = kt * 32 + lhi * 8;
    } else if (gid < 36864) {
      int q = gid - 12288;
      int lyr = q >> 13, r = q & 8191;
      int fr = r >> 6; int ct = fr >> 3, kt = fr & 7;
      col = ct * 16 + llo; kbase = kt * 32 + lhi * 8;
      if (col < 128) { W = Wm1 + lyr * 32768; }
      else { W = Wm2 + lyr * 32768; col -= 128; }
    } else {
      int q = gid - 36864;
      int lyr = q / 6144, r = q % 6144;
      int fr = r >> 6; int ct = fr / 12, kt = fr % 12;
      col = ct * 16 + llo; kbase = kt * 32 + lhi * 8;
      if (kbase < 256) { W = Wo1 + lyr * 32768; }
      else { W = Wo2 + lyr * 16384; kbase -= 256; }
    }
    f16x8 h;
#pragma unroll
    for (int e = 0; e < 8; e++) h[e] = (_Float16)W[(kbase + e) * 128 + col];
    ((f16x8*)Whf)[gid] = h;
  } else if (blk < 2336) {
    __shared__ float row[2][128];
    int rid = (blk - 2264) * 2 + (tid >> 7);   // 0..143
    int half = tid >> 7, c = tid & 127;
    int l = rid / 48, rr = rid % 48;
    row[half][c] = bond_emb[rr * 128 + c];
    __syncthreads();
    const float* W = We + l * 16384;
    float acc = 0.f;
    for (int k = 0; k < 128; k += 4) {
      acc += row[half][k] * W[k * 128 + c] +
             row[half][k + 1] * W[(k + 1) * 128 + c] +
             row[half][k + 2] * W[(k + 2) * 128 + c] +
             row[half][k + 3] * W[(k + 3) * 128 + c];
    }
    bembWeh[(l * 48 + rr) * 128 + c] = (_Float16)acc;
  } else {
    int e = (blk - 2336) * 256 + tid;
    int s = ei[e], d = ei[EE_ + e];
    int g = s >> 7, i = s & 127, j = d & 127;
    int slot = ((g << 7) + j) * 128 + i;   // receiver-major
    erank[e] = atomicAdd(&cnt[slot], 1);
  }
}

// ---------------- fused block-scan: edge-count scan + pair-flag scan
__global__ __launch_bounds__(256) void k_scanA(const int* __restrict__ cnt,
    int* __restrict__ basep, int* __restrict__ pairbase,
    int* __restrict__ bsumA, int* __restrict__ bsumF) {
  __shared__ int sA[256], sF[256];
  int t = threadIdx.x, gid = blockIdx.x * 256 + t;
  int v = cnt[gid];
  int f = v > 0 ? 1 : 0;
  sA[t] = v; sF[t] = f; __syncthreads();
  for (int st = 1; st < 256; st <<= 1) {
    int aA = sA[t], aF = sF[t];
    int bA = (t >= st) ? sA[t - st] : 0;
    int bF = (t >= st) ? sF[t - st] : 0;
    __syncthreads();
    sA[t] = aA + bA; sF[t] = aF + bF;
    __syncthreads();
  }
  basep[gid] = sA[t] - v;          // exclusive within block
  pairbase[gid] = sF[t] - f;
  if (t == 255) { bsumA[blockIdx.x] = sA[255]; bsumF[blockIdx.x] = sF[255]; }
}

// ---------------- scan of the 2048 block sums (block 0: A, block 1: F)
__global__ __launch_bounds__(256) void k_scan2d(int* __restrict__ bsumA,
                                                int* __restrict__ bsumF) {
  int* bsum = blockIdx.x ? bsumF : bsumA;
  __shared__ int s[256];
  int t = threadIdx.x;
  int v[8]; int tot = 0;
#pragma unroll
  for (int q = 0; q < 8; q++) { v[q] = bsum[t * 8 + q]; tot += v[q]; }
  s[t] = tot; __syncthreads();
  for (int st = 1; st < 256; st <<= 1) {
    int a = s[t]; int b = (t >= st) ? s[t - st] : 0;
    __syncthreads(); s[t] = a + b; __syncthreads();
  }
  int run = s[t] - tot;
#pragma unroll
  for (int q = 0; q < 8; q++) { int tmp = v[q]; bsum[t * 8 + q] = run; run += tmp; }
}

// ---------------- merged finalize: pair arrays (blocks<2048) + edge scatter
__global__ __launch_bounds__(256) void k_scanBS(const int* __restrict__ cnt,
    const int* __restrict__ basep, const int* __restrict__ pairbase,
    const int* __restrict__ bsumA, const int* __restrict__ bsumF,
    int* __restrict__ pair_total, int* __restrict__ pair_slot,
    int* __restrict__ pair_off, int* __restrict__ pair_cnt,
    const int* __restrict__ ei, const int* __restrict__ erank,
    int* __restrict__ sorted_e) {
  int blk = blockIdx.x, tid = threadIdx.x;
  if (blk < 2048) {
    int gid = blk * 256 + tid;
    int b = basep[gid] + bsumA[gid >> 8];
    int pb = pairbase[gid] + bsumF[gid >> 8];
    int c = cnt[gid];
    if (c > 0) {
      pair_slot[pb] = gid;
      pair_off[pb] = b;
      pair_cnt[pb] = c;
    }
    if (gid == SLOTS_ - 1) pair_total[0] = pb + (c > 0 ? 1 : 0);
  } else {
    int e = (blk - 2048) * 256 + tid;
    int s = ei[e], d = ei[EE_ + e];
    int g = s >> 7, i = s & 127, j = d & 127;
    int slot = ((g << 7) + j) * 128 + i;
    int pos = basep[slot] + bsumA[slot >> 8] + erank[e];
    sorted_e[pos] = e;
  }
}

// ---------------- m12 MFMA: mm = zh @ [Wm1||Wm2] + b ; one ct per wave
__global__ __launch_bounds__(256, 4) void k_m12(const _Float16* __restrict__ zh,
    const _Float16* __restrict__ Whf, const float* __restrict__ bm1,
    const float* __restrict__ bm2, _Float16* __restrict__ mm,
    unsigned* __restrict__ msgs_u, int l) {
  int tid = threadIdx.x;
  {  // msgs re-init: 1024 blocks * 256 thr * 2 = 524288
    int g0 = blockIdx.x * 256 + tid;
    unsigned kneg = fkey(NEGV);
    msgs_u[g0] = kneg;
    msgs_u[g0 + 262144] = kneg;
  }
  int wv = tid >> 6, l64 = tid & 63;
  int llo = l64 & 15, lhi = l64 >> 4;
  int tile = blockIdx.x >> 2;
  int ct = (blockIdx.x & 3) * 4 + wv;     // 0..15
  int row = tile * 16 + llo;
  f16x8 a[8];
#pragma unroll
  for (int kt = 0; kt < 8; kt++)
    a[kt] = *(const f16x8*)(zh + row * 256 + kt * 32 + lhi * 8);
  const f16x8* Bf = (const f16x8*)Whf + 12288 + l * 8192;
  int col = ct * 16 + llo;
  float bv = (col < 128) ? bm1[l * 128 + col] : bm2[l * 128 + col - 128];
  f32x4 acc = {bv, bv, bv, bv};
#pragma unroll
  for (int kt = 0; kt < 8; kt++)
    acc = __builtin_amdgcn_mfma_f32_16x16x32_f16(a[kt], Bf[(ct * 8 + kt) * 64 + l64], acc, 0, 0, 0);
#pragma unroll
  for (int reg = 0; reg < 4; reg++)
    mm[(tile * 16 + lhi * 4 + reg) * 256 + col] = (_Float16)acc[reg];
}

// ---------------- MFMA pair MLP: 64 pairs/block, LDS receiver-tile seg-max
__global__ __launch_bounds__(256, 4) void k_pairs(
    const _Float16* __restrict__ mm,
    const int* __restrict__ pair_slot, const int* __restrict__ pair_off,
    const int* __restrict__ pair_cnt, const int* __restrict__ pair_total,
    const int* __restrict__ sorted_e, const int* __restrict__ edge_attr,
    const _Float16* __restrict__ bembWeh,
    const float* __restrict__ be, const float* __restrict__ bg,
    const _Float16* __restrict__ Whf,
    const float* __restrict__ bp1, const float* __restrict__ bp2,
    unsigned* __restrict__ msgs_u, int l) {
  __shared__ int s_slot[64], s_off[64], s_cnt[64], s_lrow[64];
  __shared__ int s_scan[64];
  __shared__ int s_rid[16];
  __shared__ int s_nrecv;
  __shared__ unsigned Lmax[16 * 128];   // 8 KB receiver-tile max
  __shared__ _Float16 Uh[64 * 128];     // granule-XOR swizzled, 16 KB
  int P = pair_total[0];
  int pid0 = blockIdx.x * 64;
  if (pid0 >= P) return;
  int tid = threadIdx.x;
  {
    unsigned kneg = fkey(NEGV);
#pragma unroll
    for (int q = 0; q < 8; q++) Lmax[tid + q * 256] = kneg;
  }
  if (tid < 64) {
    int pid = pid0 + tid;
    bool va = pid < P;
    s_slot[tid] = va ? pair_slot[pid] : -1;
    s_off[tid] = va ? pair_off[pid] : 0;
    s_cnt[tid] = va ? pair_cnt[pid] : 0;
  }
  __syncthreads();
  // receiver-run indexing within block (scan of run-start flags)
  if (tid < 64) {
    int slot = s_slot[tid];
    int r = slot >= 0 ? (slot >> 7) : -1;
    int pr = (tid == 0) ? -2 : (s_slot[tid - 1] >= 0 ? (s_slot[tid - 1] >> 7) : -1);
    s_scan[tid] = (slot >= 0 && r != pr) ? 1 : 0;
  }
  __syncthreads();
  for (int st = 1; st < 64; st <<= 1) {
    int a = 0, b = 0;
    if (tid < 64) { a = s_scan[tid]; b = (tid >= st) ? s_scan[tid - st] : 0; }
    __syncthreads();
    if (tid < 64) s_scan[tid] = a + b;
    __syncthreads();
  }
  if (tid < 64) {
    int slot = s_slot[tid];
    int lr = s_scan[tid] - 1;
    s_lrow[tid] = lr;
    int r = slot >= 0 ? (slot >> 7) : -1;
    int pr = (tid == 0) ? -2 : (s_slot[tid - 1] >= 0 ? (s_slot[tid - 1] >> 7) : -1);
    if (slot >= 0 && r != pr && lr < 16) s_rid[lr] = r;
    if (tid == 63) s_nrecv = s_scan[63];
  }
  __syncthreads();

  int l64 = tid & 63, wv = tid >> 6;
  int llo = l64 & 15, lhi = l64 >> 4;
  int p = wv * 16 + llo;
  int slot = s_slot[p];
  float t32[4][8];
  if (slot >= 0) {
    int rr = slot >> 7, i = slot & 127, g = slot >> 14;
    int sn = (g << 7) + i;
#pragma unroll
    for (int kt = 0; kt < 4; kt++) {
      int c0 = kt * 32 + lhi * 8;
      f16x8 v1 = *(const f16x8*)(mm + sn * 256 + c0);         // m1[sender]
      f16x8 v2 = *(const f16x8*)(mm + rr * 256 + 128 + c0);   // m2[receiver]
      float4 e0 = *(const float4*)(be + l * 128 + c0);
      float4 e1 = *(const float4*)(be + l * 128 + c0 + 4);
      float4 g0 = *(const float4*)(bg + l * 128 + c0);
      float4 g1 = *(const float4*)(bg + l * 128 + c0 + 4);
      t32[kt][0] = (float)v1[0] + (float)v2[0] + e0.x + g0.x;
      t32[kt][1] = (float)v1[1] + (float)v2[1] + e0.y + g0.y;
      t32[kt][2] = (float)v1[2] + (float)v2[2] + e0.z + g0.z;
      t32[kt][3] = (float)v1[3] + (float)v2[3] + e0.w + g0.w;
      t32[kt][4] = (float)v1[4] + (float)v2[4] + e1.x + g1.x;
      t32[kt][5] = (float)v1[5] + (float)v2[5] + e1.y + g1.y;
      t32[kt][6] = (float)v1[6] + (float)v2[6] + e1.z + g1.z;
      t32[kt][7] = (float)v1[7] + (float)v2[7] + e1.w + g1.w;
    }
    int off = s_off[p], cn = s_cnt[p];
    for (int d = 0; d < cn; d++) {
      int eid = sorted_e[off + d];
      int a0 = edge_attr[eid * 3], a1 = edge_attr[eid * 3 + 1],
          a2 = edge_attr[eid * 3 + 2];
      const _Float16* r0 = bembWeh + (l * 48 + a0) * 128;
      const _Float16* r1 = bembWeh + (l * 48 + 16 + a1) * 128;
      const _Float16* r2 = bembWeh + (l * 48 + 32 + a2) * 128;
#pragma unroll
      for (int kt = 0; kt < 4; kt++) {
        int c0 = kt * 32 + lhi * 8;
        f16x8 x0 = *(const f16x8*)(r0 + c0);
        f16x8 x1 = *(const f16x8*)(r1 + c0);
        f16x8 x2 = *(const f16x8*)(r2 + c0);
#pragma unroll
        for (int e = 0; e < 8; e++)
          t32[kt][e] += (float)x0[e] + (float)x1[e] + (float)x2[e];
      }
    }
  } else {
#pragma unroll
    for (int kt = 0; kt < 4; kt++)
#pragma unroll
      for (int e = 0; e < 8; e++) t32[kt][e] = 0.f;
  }
  f16x8 a[4];
#pragma unroll
  for (int kt = 0; kt < 4; kt++)
#pragma unroll
    for (int e = 0; e < 8; e++) a[kt][e] = (_Float16)fmaxf(t32[kt][e], 0.f);

  const f16x8* W1f = (const f16x8*)Whf + (l * 2) * 2048;
  const f16x8* W2f = (const f16x8*)Whf + (l * 2 + 1) * 2048;
  // ---- phase 1: U = relu(T @ Wp1 + bp1) -> swizzled f16 LDS
#pragma unroll
  for (int ct = 0; ct < 8; ct++) {
    int col = ct * 16 + llo;
    float b1 = bp1[l * 128 + col];
    f32x4 acc = {b1, b1, b1, b1};
#pragma unroll
    for (int kt = 0; kt < 4; kt++)
      acc = __builtin_amdgcn_mfma_f32_16x16x32_f16(a[kt], W1f[(ct * 4 + kt) * 64 + l64], acc, 0, 0, 0);
#pragma unroll
    for (int reg = 0; reg < 4; reg++) {
      int wrow = wv * 16 + lhi * 4 + reg;
      int sg = (2 * ct + (llo >> 3)) ^ (wrow & 15);
      Uh[wrow * 128 + sg * 8 + (llo & 7)] = (_Float16)fmaxf(acc[reg], 0.f);
    }
  }
  __syncthreads();
  // ---- phase 2: V = U @ Wp2 + bp2 ; LDS receiver-tile seg-max
  f16x8 a2[4];
  int arow = wv * 16 + llo;
#pragma unroll
  for (int kt = 0; kt < 4; kt++) {
    int sg = (kt * 4 + lhi) ^ (arow & 15);
    a2[kt] = *(const f16x8*)(Uh + arow * 128 + sg * 8);
  }
#pragma unroll
  for (int ct = 0; ct < 8; ct++) {
    int col = ct * 16 + llo;
    float b2 = bp2[l * 128 + col];
    f32x4 acc = {b2, b2, b2, b2};
#pragma unroll
    for (int kt = 0; kt < 4; kt++)
      acc = __builtin_amdgcn_mfma_f32_16x16x32_f16(a2[kt], W2f[(ct * 4 + kt) * 64 + l64], acc, 0, 0, 0);
    int prev_lr = -2, prev_rr = -1; float run = 0.f;
#pragma unroll
    for (int reg = 0; reg < 4; reg++) {
      int prow = wv * 16 + lhi * 4 + reg;
      int slot2 = s_slot[prow];
      if (slot2 < 0) continue;
      int lr = s_lrow[prow];
      float v = acc[reg];
      if (lr == prev_lr) {
        run = fmaxf(run, v);
      } else {
        if (prev_lr >= 0) {
          if (prev_lr < 16) atomicMax(&Lmax[prev_lr * 128 + col], fkey(run));
          else atomicMax(&msgs_u[prev_rr * 128 + col], fkey(run));
        }
        prev_lr = lr; prev_rr = slot2 >> 7; run = v;
      }
    }
    if (prev_lr >= 0) {
      if (prev_lr < 16) atomicMax(&Lmax[prev_lr * 128 + col], fkey(run));
      else atomicMax(&msgs_u[prev_rr * 128 + col], fkey(run));
    }
  }
  __syncthreads();
  // ---- flush receiver tile: one global atomic per (receiver, col) per block
  int nr = s_nrecv; if (nr > 16) nr = 16;
  for (int base = 0; base < nr; base += 2) {
    int lr = base + (tid >> 7);
    int col = tid & 127;
    if (lr < nr)
      atomicMax(&msgs_u[s_rid[lr] * 128 + col], Lmax[lr * 128 + col]);
  }
}

// ---------------- out+LN MFMA: one ct per wave (8 waves), LDS LN reduce
__global__ __launch_bounds__(512, 2) void k_out_ln(_Float16* __restrict__ zh,
    const unsigned* __restrict__ msgs_u, const _Float16* __restrict__ Whf,
    const float* __restrict__ bo1, const float* __restrict__ bo2,
    const float* __restrict__ ln_s, const float* __restrict__ ln_b, int l) {
  __shared__ float sumA[8][16];
  __shared__ float muS[16], rsS[16];
  int tid = threadIdx.x;
  int wv = tid >> 6, l64 = tid & 63;      // wv = ct
  int llo = l64 & 15, lhi = l64 >> 4;
  int row = blockIdx.x * 16 + llo;
  f16x8 a[12];
#pragma unroll
  for (int kt = 0; kt < 8; kt++)
    a[kt] = *(const f16x8*)(zh + row * 256 + kt * 32 + lhi * 8);
#pragma unroll
  for (int kt = 8; kt < 12; kt++) {
    int k0 = (kt - 8) * 32 + lhi * 8;
    f16x8 h;
#pragma unroll
    for (int e = 0; e < 8; e++) {
      float v = funkey(msgs_u[row * 128 + k0 + e]);
      v = fmaxf(fminf(v, 60000.f), -60000.f);   // f16-safe (isolated-recv NEG)
      h[e] = (_Float16)v;
    }
    a[kt] = h;
  }
  const f16x8* Bf = (const f16x8*)Whf + 36864 + l * 6144;
  int ct = wv, col = ct * 16 + llo;
  float bv = bo1[l * 128 + col] + bo2[l * 128 + col];
  f32x4 acc = {bv, bv, bv, bv};
#pragma unroll
  for (int kt = 0; kt < 12; kt++)
    acc = __builtin_amdgcn_mfma_f32_16x16x32_f16(a[kt], Bf[(ct * 12 + kt) * 64 + l64], acc, 0, 0, 0);
  float h[4];
#pragma unroll
  for (int reg = 0; reg < 4; reg++) h[reg] = fmaxf(acc[reg], 0.f);
  // mean: reduce over llo lanes, then across 8 ct-waves via LDS
#pragma unroll
  for (int reg = 0; reg < 4; reg++) {
    float s = h[reg];
    s += __shfl_xor(s, 1, 64); s += __shfl_xor(s, 2, 64);
    s += __shfl_xor(s, 4, 64); s += __shfl_xor(s, 8, 64);
    if (llo == 0) sumA[wv][lhi * 4 + reg] = s;
  }
  __syncthreads();
  if (tid < 16) {
    float s = 0.f;
#pragma unroll
    for (int w = 0; w < 8; w++) s += sumA[w][tid];
    muS[tid] = s * (1.f / 128.f);
  }
  __syncthreads();
  // variance
#pragma unroll
  for (int reg = 0; reg < 4; reg++) {
    float d = h[reg] - muS[lhi * 4 + reg];
    float s = d * d;
    s += __shfl_xor(s, 1, 64); s += __shfl_xor(s, 2, 64);
    s += __shfl_xor(s, 4, 64); s += __shfl_xor(s, 8, 64);
    if (llo == 0) sumA[wv][lhi * 4 + reg] = s;
  }
  __syncthreads();
  if (tid < 16) {
    float s = 0.f;
#pragma unroll
    for (int w = 0; w < 8; w++) s += sumA[w][tid];
    rsS[tid] = rsqrtf(s * (1.f / 128.f) + 1e-5f);
  }
  __syncthreads();
  float sc = ln_s[l * 128 + col], bb = ln_b[l * 128 + col];
#pragma unroll
  for (int reg = 0; reg < 4; reg++) {
    int rr = lhi * 4 + reg;
    int wrow = blockIdx.x * 16 + rr;
    zh[wrow * 256 + 128 + col] =
        (_Float16)((h[reg] - muS[rr]) * rsS[rr] * sc + bb);
  }
}

// ---------------- mean pool over nodes + 2-layer head (fp32)
__global__ __launch_bounds__(128) void k_head(const _Float16* __restrict__ zh,
    const float* __restrict__ Wh1, const float* __restrict__ bh1,
    const float* __restrict__ Wh2, const float* __restrict__ bh2,
    float* __restrict__ out) {
  __shared__ float ge[128], p1[128];
  int b = blockIdx.x, t = threadIdx.x;
  float s = 0.f;
  for (int n = 0; n < 128; n++) s += (float)zh[(b * 128 + n) * 256 + 128 + t];
  ge[t] = s * (1.f / 128.f);
  __syncthreads();
  float a = bh1[t];
  for (int k = 0; k < 128; k++) a += ge[k] * Wh1[k * 128 + t];
  p1[t] = fmaxf(a, 0.f);
  __syncthreads();
  float o = bh2[t];
  for (int k = 0; k < 128; k++) o += p1[k] * Wh2[k * 128 + t];
  out[b * 128 + t] = o;
}

extern "C" void kernel_launch(void* const* d_in, const int* in_sizes, int n_in,
                              void* d_out, int out_size, void* d_ws, size_t ws_size,
                              hipStream_t stream) {
  const int* x          = (const int*)d_in[0];
  const int* edge_attr  = (const int*)d_in[1];
  const int* edge_index = (const int*)d_in[2];
  const float* atom_emb = (const float*)d_in[4];
  const float* bond_emb = (const float*)d_in[5];
  const float* Wm1 = (const float*)d_in[6];
  const float* bm1 = (const float*)d_in[7];
  const float* Wm2 = (const float*)d_in[8];
  const float* bm2 = (const float*)d_in[9];
  const float* We  = (const float*)d_in[10];
  const float* be  = (const float*)d_in[11];
  const float* bg  = (const float*)d_in[13];   // Wg dead: graph_fts == 0
  const float* Wp1 = (const float*)d_in[14];
  const float* bp1 = (const float*)d_in[15];
  const float* Wp2 = (const float*)d_in[16];
  const float* bp2 = (const float*)d_in[17];
  const float* Wo1 = (const float*)d_in[18];
  const float* bo1 = (const float*)d_in[19];
  const float* Wo2 = (const float*)d_in[20];
  const float* bo2 = (const float*)d_in[21];
  const float* ln_s = (const float*)d_in[22];
  const float* ln_b = (const float*)d_in[23];
  const float* Wh1 = (const float*)d_in[24];
  const float* bh1 = (const float*)d_in[25];
  const float* Wh2 = (const float*)d_in[26];
  const float* bh2 = (const float*)d_in[27];
  float* out = (float*)d_out;

  // workspace carve-up (~13 MB)
  int* cnt       = (int*)d_ws;                  // 524288
  int* basep     = cnt + SLOTS_;                // 524288 (block-partial scan)
  int* pairbase  = basep + SLOTS_;              // 524288
  int* bsumA     = pairbase + SLOTS_;           // 2048
  int* bsumF     = bsumA + 2048;                // 2048
  int* pair_tot  = bsumF + 2048;                // 16
  int* erank     = pair_tot + 16;               // 65536
  int* sorted_e  = erank + EE_;                 // 65536
  int* pair_slot = sorted_e + EE_;              // 65536
  int* pair_off  = pair_slot + EE_;             // 65536
  int* pair_cnt  = pair_off + EE_;              // 65536
  unsigned* msgs_u = (unsigned*)(pair_cnt + EE_);   // 524288 u32
  _Float16* zh   = (_Float16*)(msgs_u + SLOTS_);    // 4096*256 f16
  _Float16* mm   = zh + NODES_ * 256;               // 4096*256 f16
  _Float16* bembWeh = mm + NODES_ * 256;            // 3*48*128 f16
  _Float16* Whf  = bembWeh + 3 * 48 * 128;          // 55296*8 f16

  hipMemsetAsync(cnt, 0, SLOTS_ * sizeof(int), stream);

  k_pro<<<2592, 256, 0, stream>>>(x, atom_emb, zh, Wp1, Wp2, Wm1, Wm2, Wo1, Wo2,
                                  Whf, bond_emb, We, bembWeh, edge_index, cnt,
                                  erank);
  k_scanA<<<SLOTS_ / 256, 256, 0, stream>>>(cnt, basep, pairbase, bsumA, bsumF);
  k_scan2d<<<2, 256, 0, stream>>>(bsumA, bsumF);
  k_scanBS<<<2304, 256, 0, stream>>>(cnt, basep, pairbase, bsumA, bsumF,
                                     pair_tot, pair_slot, pair_off, pair_cnt,
                                     edge_index, erank, sorted_e);

  for (int l = 0; l < LL_; l++) {
    k_m12<<<1024, 256, 0, stream>>>(zh, Whf, bm1, bm2, mm, msgs_u, l);
    k_pairs<<<1024, 256, 0, stream>>>(mm, pair_slot, pair_off, pair_cnt,
                                      pair_tot, sorted_e, edge_attr, bembWeh,
                                      be, bg, Whf, bp1, bp2, msgs_u, l);
    k_out_ln<<<NODES_ / 16, 512, 0, stream>>>(zh, msgs_u, Whf, bo1, bo2,
                                              ln_s, ln_b, l);
  }
  k_head<<<NB_, 128, 0, stream>>>(zh, Wh1, bh1, Wh2, bh2, out);
}